// Round 6
// baseline (510.188 us; speedup 1.0000x reference)
//
#include <hip/hip_runtime.h>
#include <float.h>
#include <math.h>

#define N_ROWS 4096
#define M_TGT  65536
#define DDIM   256

// ---------------------------------------------------------------------------
// Shared types/helpers
// ---------------------------------------------------------------------------
typedef short bf16x8 __attribute__((ext_vector_type(8)));
typedef float f32x4 __attribute__((ext_vector_type(4)));
typedef float f32x16 __attribute__((ext_vector_type(16)));
typedef unsigned short ushort4_t __attribute__((ext_vector_type(4)));

__device__ inline unsigned short f2bf(float f) {
  union { float f; unsigned u; } c; c.f = f;
  unsigned u = c.u;
  unsigned r = (u + 0x7FFFu + ((u >> 16) & 1u)) >> 16;  // RNE
  return (unsigned short)r;
}

__device__ inline void gload_lds16(const void* g, void* l) {
  __builtin_amdgcn_global_load_lds(
      (const __attribute__((address_space(1))) void*)g,
      (__attribute__((address_space(3))) void*)l, 16, 0, 0);
}

// ---------------------------------------------------------------------------
// Fused fp32->bf16 convert + row norm for BOTH x and t. One wave per row.
// ---------------------------------------------------------------------------
__global__ __launch_bounds__(256) void conv_norm_all(
    const float* __restrict__ x, const float* __restrict__ t,
    unsigned short* __restrict__ xb, unsigned short* __restrict__ tb,
    float* __restrict__ xn, float* __restrict__ tn) {
  int wave = threadIdx.x >> 6;
  int lane = threadIdx.x & 63;
  int row  = blockIdx.x * 4 + wave;
  const float* src;
  unsigned short* db;
  float* dn;
  if (row < N_ROWS) {
    src = x + (size_t)row * DDIM;
    db  = xb + (size_t)row * DDIM;
    dn  = xn + row;
  } else {
    int r = row - N_ROWS;
    if (r >= M_TGT) return;
    src = t + (size_t)r * DDIM;
    db  = tb + (size_t)r * DDIM;
    dn  = tn + r;
  }
  float4 v = *(const float4*)(src + lane * 4);
  float ss = v.x * v.x + v.y * v.y + v.z * v.z + v.w * v.w;
  ushort4_t o;
  o[0] = f2bf(v.x); o[1] = f2bf(v.y); o[2] = f2bf(v.z); o[3] = f2bf(v.w);
  *(ushort4_t*)(db + lane * 4) = o;
  #pragma unroll
  for (int off = 32; off > 0; off >>= 1) ss += __shfl_xor(ss, off, 64);
  if (lane == 0) *dn = ss;
}

// ---------------------------------------------------------------------------
// bf16 MFMA screening GEMM — TLP-first design.
// 128x128 tile, 4 waves (2Mx2N), BK=32 double-buffered (32 KB LDS),
// __launch_bounds__(256,4) -> 4 blocks/CU: prologue/epilogue/barrier stalls
// of one block hide under the other 3 (m114 mechanism).
// MFMA: 32x32x16 (2x2 frags/wave, acc 64 VGPR) — half the instructions,
// higher ceiling than 16x16x32. Counted vmcnt(4), never 0 until tail.
// Addressing: all K-step deltas are literals folded into load immediates.
// LDS swizzle: 64B rows = 4x16B slots, phys p = s ^ ((row>>1)&3); stage
// source pre-permuted with the same involution (rule 21, conflict-free).
// Output: per (row, 128-col tile) min of (tn[col] - 2*dot) into bmv[cb][row].
// ---------------------------------------------------------------------------
#define GBM 128
#define GBN 128
#define NK  8                       // K-steps of 32
#define NCB 512                     // 128-col groups
#define MARGIN 1.5f

#define STG(T)                                                                \
  { char* dA_ = sbase + (((T) & 1) * 8192) + tid * 16;                        \
    gload_lds16(gA0 + (T) * 32, dA_);                                         \
    gload_lds16(gA1 + (T) * 32, dA_ + 4096);                                  \
    gload_lds16(gB0 + (T) * 32, dA_ + 16384);                                 \
    gload_lds16(gB1 + (T) * 32, dA_ + 20480);                                 \
  }

#define MFMA32(a, b, c) __builtin_amdgcn_mfma_f32_32x32x16_bf16(a, b, c, 0, 0, 0)

#define KSTEP(T, VN)                                                          \
  { if ((T) + 1 < NK) STG((T) + 1)                                            \
    asm volatile("s_waitcnt vmcnt(" #VN ")" ::: "memory");                    \
    __builtin_amdgcn_sched_barrier(0);                                        \
    __builtin_amdgcn_s_barrier();                                             \
    bf16x8 a00 = *(const bf16x8*)(sbase + (adrA0 + (((T) & 1) * 8192)));      \
    bf16x8 a10 = *(const bf16x8*)(sbase + (adrA1 + (((T) & 1) * 8192)));      \
    bf16x8 b00 = *(const bf16x8*)(sbase + (adrB0 + (((T) & 1) * 8192)));      \
    bf16x8 b10 = *(const bf16x8*)(sbase + (adrB1 + (((T) & 1) * 8192)));      \
    bf16x8 a01 = *(const bf16x8*)(sbase + ((adrA0 ^ 32) + (((T) & 1) * 8192)));\
    bf16x8 a11 = *(const bf16x8*)(sbase + ((adrA1 ^ 32) + (((T) & 1) * 8192)));\
    bf16x8 b01 = *(const bf16x8*)(sbase + ((adrB0 ^ 32) + (((T) & 1) * 8192)));\
    bf16x8 b11 = *(const bf16x8*)(sbase + ((adrB1 ^ 32) + (((T) & 1) * 8192)));\
    asm volatile("s_waitcnt lgkmcnt(4)" ::: "memory");                        \
    __builtin_amdgcn_sched_barrier(0);                                        \
    __builtin_amdgcn_s_setprio(1);                                            \
    acc00 = MFMA32(a00, b00, acc00);                                          \
    acc01 = MFMA32(a00, b10, acc01);                                          \
    acc10 = MFMA32(a10, b00, acc10);                                          \
    acc11 = MFMA32(a10, b10, acc11);                                          \
    __builtin_amdgcn_s_setprio(0);                                            \
    asm volatile("s_waitcnt lgkmcnt(0)" ::: "memory");                        \
    __builtin_amdgcn_sched_barrier(0);                                        \
    __builtin_amdgcn_s_setprio(1);                                            \
    acc00 = MFMA32(a01, b01, acc00);                                          \
    acc01 = MFMA32(a01, b11, acc01);                                          \
    acc10 = MFMA32(a11, b01, acc10);                                          \
    acc11 = MFMA32(a11, b11, acc11);                                          \
    __builtin_amdgcn_s_setprio(0);                                            \
    __builtin_amdgcn_s_barrier();                                             \
  }

__global__ __launch_bounds__(256, 4) void nn_gemm_bf16(
    const unsigned short* __restrict__ xb, const unsigned short* __restrict__ tb,
    const float* __restrict__ tn, float* __restrict__ bmv) {
  // layout: [mat][parity][128 rows x 32 k] bf16 ; A at 0, B at +16384
  __shared__ __align__(16) unsigned short sAB[2][2][GBM * 32];  // 32 KB
  char* sbase = (char*)&sAB[0][0][0];

  const int tid  = threadIdx.x;
  const int lane = tid & 63;
  const int wid  = tid >> 6;        // 0..3
  const int wr   = wid >> 1;        // M half
  const int wc   = wid & 1;         // N half
  const int ln   = lane & 31;
  const int h    = lane >> 5;

  // XCD-aware, B-panel-reuse ordering: 16384 = 8 xcd * (32 rb * 64 cb)
  const int bid = blockIdx.x;
  const int xcd = bid & 7;
  const int wgi = bid >> 3;
  const int rb  = wgi & 31;                  // fastest: B col-panel L2 reuse
  const int cb  = xcd * 64 + (wgi >> 5);     // 0..511
  const int row0 = rb * GBM;
  const int col0 = cb * GBN;

  // staging map: chunk q = tid (0..255) covers rows 0..63; +256 -> rows 64..127
  // row = q>>2, phys slot = q&3, logical s = (q&3) ^ ((q>>3)&3)
  const int rS = tid >> 2;
  const int sS = (tid & 3) ^ ((tid >> 3) & 3);
  const unsigned short* gA0 = xb + (size_t)(row0 + rS) * DDIM + sS * 8;
  const unsigned short* gA1 = gA0 + (size_t)64 * DDIM;
  const unsigned short* gB0 = tb + (size_t)(col0 + rS) * DDIM + sS * 8;
  const unsigned short* gB1 = gB0 + (size_t)64 * DDIM;

  // frag read addresses (kk=0); kk=1 = ^32, parity = +8192 (literals)
  const int rA0 = wr * 64 + ln;
  const int rA1 = rA0 + 32;
  const int rB0 = wc * 64 + ln;
  const int rB1 = rB0 + 32;
  const int adrA0 = rA0 * 64 + ((h ^ ((rA0 >> 1) & 3)) * 16);
  const int adrA1 = rA1 * 64 + ((h ^ ((rA1 >> 1) & 3)) * 16);
  const int adrB0 = 16384 + rB0 * 64 + ((h ^ ((rB0 >> 1) & 3)) * 16);
  const int adrB1 = 16384 + rB1 * 64 + ((h ^ ((rB1 >> 1) & 3)) * 16);

  f32x16 acc00 = {0}, acc01 = {0}, acc10 = {0}, acc11 = {0};

  STG(0)
  KSTEP(0, 4) KSTEP(1, 4) KSTEP(2, 4) KSTEP(3, 4)
  KSTEP(4, 4) KSTEP(5, 4) KSTEP(6, 4) KSTEP(7, 0)

  // ---- epilogue: per-row min of (tn[col] - 2*dot) over this 128-col tile ----
  const float tnc0 = tn[col0 + wc * 64 + ln];
  const float tnc1 = tn[col0 + wc * 64 + 32 + ln];
  float* emin = (float*)sbase;        // [2 wc][128 rows], safe after last barrier

  #pragma unroll
  for (int m = 0; m < 2; ++m) {
    f32x16 cn0 = m ? acc10 : acc00;
    f32x16 cn1 = m ? acc11 : acc01;
    float bv[16];
    #pragma unroll
    for (int j = 0; j < 16; ++j)
      bv[j] = fminf(tnc0 - 2.0f * cn0[j], tnc1 - 2.0f * cn1[j]);
    #pragma unroll
    for (int off = 1; off < 32; off <<= 1)
      #pragma unroll
      for (int j = 0; j < 16; ++j)
        bv[j] = fminf(bv[j], __shfl_xor(bv[j], off, 64));
    if (ln == 0) {
      #pragma unroll
      for (int j = 0; j < 16; ++j) {
        int r = wr * 64 + m * 32 + (j & 3) + 8 * (j >> 2) + 4 * h;
        emin[wc * 128 + r] = bv[j];
      }
    }
  }
  __syncthreads();
  if (tid < 128)
    bmv[(size_t)cb * N_ROWS + row0 + tid] = fminf(emin[tid], emin[128 + tid]);
}

// ---------------------------------------------------------------------------
// Per-row candidate selection + exact fp32 verification. Wave per row.
// ---------------------------------------------------------------------------
__global__ __launch_bounds__(256) void nn_exact(
    const float* __restrict__ x, const float* __restrict__ t,
    const float* __restrict__ xn, const float* __restrict__ tn,
    const float* __restrict__ bmv, float* __restrict__ out) {
  const int tid  = threadIdx.x;
  const int wid  = tid >> 6;
  const int lane = tid & 63;
  const int row  = blockIdx.x * 4 + wid;

  float sv[8];
  float lmin = FLT_MAX;
  #pragma unroll
  for (int i = 0; i < 8; ++i) {
    sv[i] = bmv[(size_t)(i * 64 + lane) * N_ROWS + row];
    lmin = fminf(lmin, sv[i]);
  }
  #pragma unroll
  for (int off = 32; off > 0; off >>= 1)
    lmin = fminf(lmin, __shfl_xor(lmin, off, 64));
  const float thr = lmin + MARGIN;

  const float xnr = xn[row];
  const float* xrow = x + (size_t)row * DDIM;
  float best = FLT_MAX;
  int   bidx = 0x7FFFFFFF;

  #pragma unroll 1
  for (int i = 0; i < 8; ++i) {
    unsigned long long mask = __ballot(sv[i] <= thr);
    while (mask) {
      int src = __ffsll((unsigned long long)mask) - 1;
      mask &= mask - 1;
      int cbk = i * 64 + src;
      int c0 = cbk * 128 + lane;
      const float* t0 = t + (size_t)c0 * DDIM;
      const float* t1 = t0 + (size_t)64 * DDIM;
      float a0 = 0.0f, a1 = 0.0f;
      // serial k-ascending fp32 FMA chain per col (deterministic, exact)
      #pragma unroll
      for (int kq = 0; kq < DDIM; kq += 4) {
        float4 xv = *(const float4*)(xrow + kq);
        float4 u  = *(const float4*)(t0 + kq);
        float4 w  = *(const float4*)(t1 + kq);
        a0 = fmaf(xv.x, u.x, a0); a0 = fmaf(xv.y, u.y, a0);
        a0 = fmaf(xv.z, u.z, a0); a0 = fmaf(xv.w, u.w, a0);
        a1 = fmaf(xv.x, w.x, a1); a1 = fmaf(xv.y, w.y, a1);
        a1 = fmaf(xv.z, w.z, a1); a1 = fmaf(xv.w, w.w, a1);
      }
      float d0 = xnr + tn[c0] - 2.0f * a0;
      float d1 = xnr + tn[c0 + 64] - 2.0f * a1;
      if (d0 < best || (d0 == best && c0 < bidx)) { best = d0; bidx = c0; }
      int c1 = c0 + 64;
      if (d1 < best || (d1 == best && c1 < bidx)) { best = d1; bidx = c1; }
    }
  }
  #pragma unroll
  for (int off = 1; off < 64; off <<= 1) {
    float vo = __shfl_xor(best, off, 64);
    int   io = __shfl_xor(bidx, off, 64);
    if (vo < best || (vo == best && io < bidx)) { best = vo; bidx = io; }
  }
  if (lane == 0) {
    out[row] = sqrtf(fmaxf(best, 0.0f));
    out[N_ROWS + row] = (float)bidx;
  }
}

// ---------------------------------------------------------------------------
// Fallback fp32 path (if ws too small) — round-1 proven
// ---------------------------------------------------------------------------
#define BM 64
#define BN 64
#define KC 16
#define S_STRIPS 32
#define PADM 68

__global__ __launch_bounds__(256) void norms_kernel_fb(
    const float* __restrict__ x, const float* __restrict__ t,
    float* __restrict__ xn, float* __restrict__ tn) {
  int wave = threadIdx.x >> 6;
  int lane = threadIdx.x & 63;
  int row  = blockIdx.x * 4 + wave;
  const float* src; float* dst;
  if (row < N_ROWS) { src = x + (size_t)row * DDIM; dst = xn + row; }
  else {
    int r = row - N_ROWS;
    if (r >= M_TGT) return;
    src = t + (size_t)r * DDIM; dst = tn + r;
  }
  float4 v = *(const float4*)(src + lane * 4);
  float s = v.x * v.x + v.y * v.y + v.z * v.z + v.w * v.w;
  #pragma unroll
  for (int off = 32; off > 0; off >>= 1) s += __shfl_xor(s, off, 64);
  if (lane == 0) *dst = s;
}

__global__ __launch_bounds__(256) void nn_main_fb(
    const float* __restrict__ x, const float* __restrict__ t,
    const float* __restrict__ xn, const float* __restrict__ tn,
    float* __restrict__ pmin, int* __restrict__ pidx) {
  __shared__ float sx[KC][PADM];
  __shared__ float st[KC][PADM];
  const int tid = threadIdx.x;
  const int rb = blockIdx.x;
  const int strip = blockIdx.y;
  const int tx = tid & 15, ty = tid >> 4;
  const int row0 = rb * BM;
  const int col_start = strip * (M_TGT / S_STRIPS);
  const int ntiles = (M_TGT / S_STRIPS) / BN;
  const int srow = tid >> 2;
  const int kq = (tid & 3) * 4;

  float runMin[4]; int runIdx[4];
  #pragma unroll
  for (int r = 0; r < 4; ++r) { runMin[r] = FLT_MAX; runIdx[r] = 0; }
  float xnr[4];
  #pragma unroll
  for (int r = 0; r < 4; ++r) xnr[r] = xn[row0 + ty * 4 + r];

  for (int tile = 0; tile < ntiles; ++tile) {
    const int cbk = col_start + tile * BN;
    float acc[4][4];
    #pragma unroll
    for (int r = 0; r < 4; ++r)
      #pragma unroll
      for (int c = 0; c < 4; ++c) acc[r][c] = 0.0f;
    #pragma unroll 1
    for (int kc = 0; kc < DDIM; kc += KC) {
      float4 xv = *(const float4*)(x + (size_t)(row0 + srow) * DDIM + kc + kq);
      float4 tv = *(const float4*)(t + (size_t)(cbk + srow) * DDIM + kc + kq);
      __syncthreads();
      sx[kq + 0][srow] = xv.x; sx[kq + 1][srow] = xv.y;
      sx[kq + 2][srow] = xv.z; sx[kq + 3][srow] = xv.w;
      st[kq + 0][srow] = tv.x; st[kq + 1][srow] = tv.y;
      st[kq + 2][srow] = tv.z; st[kq + 3][srow] = tv.w;
      __syncthreads();
      #pragma unroll
      for (int k = 0; k < KC; ++k) {
        float4 xa = *(const float4*)&sx[k][ty * 4];
        float4 tb2 = *(const float4*)&st[k][tx * 4];
        float xr[4] = {xa.x, xa.y, xa.z, xa.w};
        float tc[4] = {tb2.x, tb2.y, tb2.z, tb2.w};
        #pragma unroll
        for (int r = 0; r < 4; ++r)
          #pragma unroll
          for (int c = 0; c < 4; ++c)
            acc[r][c] = fmaf(xr[r], tc[c], acc[r][c]);
      }
    }
    #pragma unroll
    for (int r = 0; r < 4; ++r)
      #pragma unroll
      for (int c = 0; c < 4; ++c) {
        int col = cbk + tx * 4 + c;
        float d2 = xnr[r] + tn[col] - 2.0f * acc[r][c];
        if (d2 < runMin[r]) { runMin[r] = d2; runIdx[r] = col; }
      }
  }
  __syncthreads();
  float* redv = &sx[0][0];
  int*   redi = (int*)&st[0][0];
  #pragma unroll
  for (int r = 0; r < 4; ++r) {
    int lrow = ty * 4 + r;
    redv[lrow * 16 + tx] = runMin[r];
    redi[lrow * 16 + tx] = runIdx[r];
  }
  __syncthreads();
  if (tid < 64) {
    float best = FLT_MAX; int bi = 0;
    #pragma unroll
    for (int j = 0; j < 16; ++j) {
      float v = redv[tid * 16 + j];
      int   i = redi[tid * 16 + j];
      if (v < best || (v == best && i < bi)) { best = v; bi = i; }
    }
    int grow = row0 + tid;
    pmin[(size_t)grow * S_STRIPS + strip] = best;
    pidx[(size_t)grow * S_STRIPS + strip] = bi;
  }
}

__global__ __launch_bounds__(256) void reduce_final_fb(
    const float* __restrict__ pmin, const int* __restrict__ pidx,
    float* __restrict__ out) {
  int row = blockIdx.x * 256 + threadIdx.x;
  if (row >= N_ROWS) return;
  float best = FLT_MAX; int bi = 0;
  #pragma unroll 4
  for (int s = 0; s < S_STRIPS; ++s) {
    float v = pmin[(size_t)row * S_STRIPS + s];
    int   i = pidx[(size_t)row * S_STRIPS + s];
    if (v < best || (v == best && i < bi)) { best = v; bi = i; }
  }
  out[row] = sqrtf(fmaxf(best, 0.0f));
  out[N_ROWS + row] = (float)bi;
}

// ---------------------------------------------------------------------------
extern "C" void kernel_launch(void* const* d_in, const int* in_sizes, int n_in,
                              void* d_out, int out_size, void* d_ws, size_t ws_size,
                              hipStream_t stream) {
  const float* x = (const float*)d_in[0];
  const float* t = (const float*)d_in[1];
  float* ws = (float*)d_ws;
  float* out = (float*)d_out;

  float* xn = ws;                       // 4096
  float* tn = ws + N_ROWS;              // 65536

  // fast-path ws layout (floats): xn | tn | bmv[512*4096] | xb | tb
  const size_t f_bmv = (size_t)N_ROWS + M_TGT;
  const size_t f_xb  = f_bmv + (size_t)N_ROWS * NCB;
  const size_t f_tb  = f_xb + ((size_t)N_ROWS * DDIM) / 2;       // bf16 halves
  const size_t need_bytes = (f_tb + ((size_t)M_TGT * DDIM) / 2) * sizeof(float);

  if (ws_size >= need_bytes) {
    float* bmv = ws + f_bmv;
    unsigned short* xb = (unsigned short*)(ws + f_xb);
    unsigned short* tb = (unsigned short*)(ws + f_tb);

    conv_norm_all<<<(N_ROWS + M_TGT) / 4, 256, 0, stream>>>(x, t, xb, tb, xn, tn);

    nn_gemm_bf16<<<(N_ROWS / GBM) * (M_TGT / GBN), 256, 0, stream>>>(xb, tb, tn, bmv);

    nn_exact<<<N_ROWS / 4, 256, 0, stream>>>(x, t, xn, tn, bmv, out);
  } else {
    norms_kernel_fb<<<(N_ROWS + M_TGT) / 4, 256, 0, stream>>>(x, t, xn, tn);
    float* pmin = ws + N_ROWS + M_TGT;
    int*   pidx = (int*)(ws + N_ROWS + M_TGT + (size_t)N_ROWS * S_STRIPS);
    dim3 grid(N_ROWS / BM, S_STRIPS);
    nn_main_fb<<<grid, 256, 0, stream>>>(x, t, xn, tn, pmin, pidx);
    reduce_final_fb<<<(N_ROWS + 255) / 256, 256, 0, stream>>>(pmin, pidx, out);
  }
}

// Round 7
// 360.701 us; speedup vs baseline: 1.4144x; 1.4144x over previous
//
#include <hip/hip_runtime.h>
#include <float.h>
#include <math.h>

#define N_ROWS 4096
#define M_TGT  65536
#define DDIM   256

// ---------------------------------------------------------------------------
// Shared types/helpers
// ---------------------------------------------------------------------------
typedef short bf16x8 __attribute__((ext_vector_type(8)));
typedef float f32x4 __attribute__((ext_vector_type(4)));
typedef unsigned short ushort4_t __attribute__((ext_vector_type(4)));

__device__ inline unsigned short f2bf(float f) {
  union { float f; unsigned u; } c; c.f = f;
  unsigned u = c.u;
  unsigned r = (u + 0x7FFFu + ((u >> 16) & 1u)) >> 16;  // RNE
  return (unsigned short)r;
}

__device__ inline void gload_lds16(const void* g, void* l) {
  __builtin_amdgcn_global_load_lds(
      (const __attribute__((address_space(1))) void*)g,
      (__attribute__((address_space(3))) void*)l, 16, 0, 0);
}

#define MFMA16(a, b, c) __builtin_amdgcn_mfma_f32_16x16x32_bf16(a, b, c, 0, 0, 0)

// ---------------------------------------------------------------------------
// Fused fp32->bf16 convert + row norm for BOTH x and t. One wave per row.
// ---------------------------------------------------------------------------
__global__ __launch_bounds__(256) void conv_norm_all(
    const float* __restrict__ x, const float* __restrict__ t,
    unsigned short* __restrict__ xb, unsigned short* __restrict__ tb,
    float* __restrict__ xn, float* __restrict__ tn) {
  int wave = threadIdx.x >> 6;
  int lane = threadIdx.x & 63;
  int row  = blockIdx.x * 4 + wave;
  const float* src;
  unsigned short* db;
  float* dn;
  if (row < N_ROWS) {
    src = x + (size_t)row * DDIM;
    db  = xb + (size_t)row * DDIM;
    dn  = xn + row;
  } else {
    int r = row - N_ROWS;
    if (r >= M_TGT) return;
    src = t + (size_t)r * DDIM;
    db  = tb + (size_t)r * DDIM;
    dn  = tn + r;
  }
  float4 v = *(const float4*)(src + lane * 4);
  float ss = v.x * v.x + v.y * v.y + v.z * v.z + v.w * v.w;
  ushort4_t o;
  o[0] = f2bf(v.x); o[1] = f2bf(v.y); o[2] = f2bf(v.z); o[3] = f2bf(v.w);
  *(ushort4_t*)(db + lane * 4) = o;
  #pragma unroll
  for (int off = 32; off > 0; off >>= 1) ss += __shfl_xor(ss, off, 64);
  if (lane == 0) *dn = ss;
}

// ---------------------------------------------------------------------------
// bf16 MFMA screening GEMM — A-resident-in-registers, long N-loop.
// Block: 128 rows x 2048 cols. 4 waves (2 mh x 2 nh). A = 64 rows x 256 K per
// wave in 128 VGPR (32 bf16x8 frags). N-loop: 32 strips of 64 cols; B strip
// double-buffered in LDS (2 x 32 KB) with counted vmcnt(8) (1-deep prefetch).
// Per strip per wave: 16 ds_read_b128 (B only) + 64 MFMA 16x16x32.
// Swizzle (r3-proven): 512B rows = 32 x 16B slots, phys p = s ^ (row&7);
// stage source pre-permuted (rule 21).
// Epilogue: per-lane running min over 2 strips; cross-lane reduce per 128-col
// group -> smin LDS -> merged wave writes bmv[g][row] (coalesced).
// tn for the block's 2048 cols staged once into LDS (8 KB).
// LDS total: 64 KB B + 8 KB tn + 1 KB smin = 73 KB -> 2 blocks/CU.
// ---------------------------------------------------------------------------
#define NCB 512                     // 128-col groups
#define MARGIN 1.5f

#define STAGEB_ADV()                                                          \
  { _Pragma("unroll")                                                         \
    for (int i_ = 0; i_ < 8; ++i_)                                            \
      gload_lds16(tbs + soff[i_], Bbc + stgpar * 32768 + (i_ * 256 + tid) * 16); \
    tbs += 64 * 256; stgpar ^= 1; }

#define STRIP_BODY(PAR, ODD)                                                  \
  {                                                                           \
    const char* Bp = Bbc + (PAR) * 32768;                                     \
    float t0 = tnl[tnidx + colw0];                                            \
    float t1 = tnl[tnidx + colw1];                                            \
    tnidx += 64;                                                              \
    f32x4 acc[4][2];                                                          \
    _Pragma("unroll")                                                         \
    for (int m = 0; m < 4; ++m) { acc[m][0] = zero4; acc[m][1] = zero4; }     \
    __builtin_amdgcn_s_setprio(1);                                            \
    _Pragma("unroll")                                                         \
    for (int kk = 0; kk < 8; ++kk) {                                          \
      bf16x8 b0 = *(const bf16x8*)(Bp + colw0 * 512 +                         \
                                   (((kk * 4 + cg) ^ (colw0 & 7)) << 4));     \
      bf16x8 b1 = *(const bf16x8*)(Bp + colw1 * 512 +                         \
                                   (((kk * 4 + cg) ^ (colw1 & 7)) << 4));     \
      _Pragma("unroll")                                                       \
      for (int m = 0; m < 4; ++m) {                                           \
        acc[m][0] = MFMA16(af[m][kk], b0, acc[m][0]);                         \
        acc[m][1] = MFMA16(af[m][kk], b1, acc[m][1]);                         \
      }                                                                       \
    }                                                                         \
    __builtin_amdgcn_s_setprio(0);                                            \
    _Pragma("unroll")                                                         \
    for (int m = 0; m < 4; ++m)                                               \
      _Pragma("unroll")                                                       \
      for (int j = 0; j < 4; ++j)                                             \
        vrun[m][j] = fminf(vrun[m][j],                                        \
                           fminf(fmaf(-2.0f, acc[m][0][j], t0),               \
                                 fmaf(-2.0f, acc[m][1][j], t1)));             \
    if (ODD) {                                                                \
      _Pragma("unroll")                                                       \
      for (int m = 0; m < 4; ++m) {                                           \
        f32x4 rv;                                                             \
        _Pragma("unroll")                                                     \
        for (int j = 0; j < 4; ++j) {                                         \
          float v = vrun[m][j];                                               \
          v = fminf(v, __shfl_xor(v, 1, 64));                                 \
          v = fminf(v, __shfl_xor(v, 2, 64));                                 \
          v = fminf(v, __shfl_xor(v, 4, 64));                                 \
          v = fminf(v, __shfl_xor(v, 8, 64));                                 \
          rv[j] = v;                                                          \
          vrun[m][j] = FLT_MAX;                                               \
        }                                                                     \
        if (l4 == 0)                                                          \
          *(f32x4*)&smin[nh][mh * 64 + m * 16 + cg * 4] = rv;                 \
      }                                                                       \
    }                                                                         \
    __builtin_amdgcn_s_barrier();  /* #2: reads done before next stage */     \
    if (ODD) {                                                                \
      if (tid < 128)                                                          \
        bmv[(size_t)gcur * N_ROWS + row0 + tid] =                             \
            fminf(smin[0][tid], smin[1][tid]);                                \
      gcur++;                                                                 \
    }                                                                         \
  }

__global__ __launch_bounds__(256, 2) void nn_gemm_bf16(
    const unsigned short* __restrict__ xb, const unsigned short* __restrict__ tb,
    const float* __restrict__ tng, float* __restrict__ bmv) {
  __shared__ __align__(16) unsigned short Bbuf[2][64 * 256];  // 64 KB (also A bounce)
  __shared__ __align__(16) float tnl[2048];                   // 8 KB
  __shared__ float smin[2][128];                              // 1 KB
  char* Bbc = (char*)&Bbuf[0][0];

  const int tid  = threadIdx.x;
  const int lane = tid & 63;
  const int wid  = tid >> 6;
  const int mh   = wid >> 1;            // row half
  const int nh   = wid & 1;             // col half (of 64-col strip)
  const int l4   = lane & 15;
  const int cg   = lane >> 4;
  const int colw0 = nh * 32 + l4;       // wave col 0..63 within strip
  const int colw1 = colw0 + 16;
  const f32x4 zero4 = {0.0f, 0.0f, 0.0f, 0.0f};

  // grid: 1024 = 8 xcd * (32 rb * 4 csl); cs-range per XCD -> 4MB tb slice in L2
  const int bid = blockIdx.x;
  const int xcd = bid & 7;
  const int w   = bid >> 3;
  const int rb  = w & 31;
  const int cs  = xcd * 4 + (w >> 5);   // 0..31, block col-strip (2048 cols)
  const int row0 = rb * 128;
  const int col0 = cs * 2048;

  // staging source offsets (shorts) for one 64x256 strip:
  // chunk q = i*256+tid -> col=q>>5, phys slot=q&31, logical s = (q&31)^(col&7)
  int soff[8];
  #pragma unroll
  for (int i = 0; i < 8; ++i) {
    int q = i * 256 + tid;
    soff[i] = ((q >> 5) << 8) + (((q & 31) ^ ((q >> 5) & 7)) << 3);
  }

  // ---- prologue: stage A (64 KB -> B area) + tn (8 KB) ----
  #pragma unroll
  for (int i = 0; i < 16; ++i) {
    int q = i * 256 + tid;
    int arow = q >> 5;
    int s = (q & 31) ^ (arow & 7);
    gload_lds16(xb + (size_t)(row0 + arow) * DDIM + s * 8, Bbc + q * 16);
  }
  #pragma unroll
  for (int i = 0; i < 2; ++i) {
    int q = i * 256 + tid;
    gload_lds16(tng + col0 + q * 4, (char*)tnl + q * 16);
  }
  asm volatile("s_waitcnt vmcnt(0)" ::: "memory");
  __builtin_amdgcn_sched_barrier(0);
  __builtin_amdgcn_s_barrier();

  // ---- A fragments into registers: af[m][kk], rows mh*64+m*16+l4 ----
  bf16x8 af[4][8];
  #pragma unroll
  for (int m = 0; m < 4; ++m) {
    int r = mh * 64 + m * 16 + l4;
    #pragma unroll
    for (int kk = 0; kk < 8; ++kk) {
      int p = (kk * 4 + cg) ^ (r & 7);
      af[m][kk] = *(const bf16x8*)(Bbc + r * 512 + p * 16);
    }
  }
  asm volatile("s_waitcnt lgkmcnt(0)" ::: "memory");
  __builtin_amdgcn_sched_barrier(0);
  __builtin_amdgcn_s_barrier();      // all waves done reading A area

  // ---- N-loop over 32 strips of 64 cols ----
  const unsigned short* tbs = tb + (size_t)col0 * DDIM;  // next stage target
  int stgpar = 0;
  int tnidx = 0;
  int gcur = cs * 16;
  float vrun[4][4];
  #pragma unroll
  for (int m = 0; m < 4; ++m)
    #pragma unroll
    for (int j = 0; j < 4; ++j) vrun[m][j] = FLT_MAX;

  STAGEB_ADV();                       // strip 0 -> buf0

  for (int it = 0; it < 16; ++it) {
    // strip n = 2*it (even, buf0)
    STAGEB_ADV();                     // stage strip 2*it+1 -> buf1
    asm volatile("s_waitcnt vmcnt(8)" ::: "memory");
    __builtin_amdgcn_sched_barrier(0);
    __builtin_amdgcn_s_barrier();
    STRIP_BODY(0, 0)

    // strip n = 2*it+1 (odd, buf1)
    if (it < 15) {
      STAGEB_ADV();                   // stage strip 2*it+2 -> buf0
      asm volatile("s_waitcnt vmcnt(8)" ::: "memory");
    } else {
      asm volatile("s_waitcnt vmcnt(0)" ::: "memory");
    }
    __builtin_amdgcn_sched_barrier(0);
    __builtin_amdgcn_s_barrier();
    STRIP_BODY(1, 1)
  }
}

// ---------------------------------------------------------------------------
// Candidate selection + exact fp32 verification. 256 blocks x 16 rows.
// Two coalesced passes over bmv (no transpose needed); packed-u64 atomicMin
// (clamped-d2 bits << 32 | col) gives order-independent first-index argmin.
// ---------------------------------------------------------------------------
__global__ __launch_bounds__(256) void nn_exact(
    const float* __restrict__ x, const float* __restrict__ t,
    const float* __restrict__ xn, const float* __restrict__ tn,
    const float* __restrict__ bmv, float* __restrict__ out) {
  __shared__ float red[256];
  __shared__ unsigned pr[2048];
  __shared__ int cnt;
  __shared__ unsigned long long best[16];

  const int tid = threadIdx.x;
  const int r   = tid & 15;
  const int gq  = tid >> 4;
  const int row0 = blockIdx.x * 16;

  // pass 1: per-row global min over the 512 group-mins (coalesced)
  float rm = FLT_MAX;
  #pragma unroll 4
  for (int j = 0; j < 32; ++j)
    rm = fminf(rm, bmv[(size_t)(gq + 16 * j) * N_ROWS + row0 + r]);
  red[tid] = rm;
  if (tid < 16) best[tid] = ~0ull;
  __syncthreads();
  for (int s = 128; s >= 16; s >>= 1) {
    if (tid < s) red[tid] = fminf(red[tid], red[tid + s]);
    __syncthreads();
  }
  const float thr = red[r] + MARGIN;

  // pass 2: chunked candidate collection + exact verify
  for (int gb = 0; gb < NCB; gb += 128) {
    if (tid == 0) cnt = 0;
    __syncthreads();
    #pragma unroll
    for (int j = 0; j < 8; ++j) {
      int g = gb + gq + 16 * j;
      float v = bmv[(size_t)g * N_ROWS + row0 + r];
      if (v <= thr) {
        int p = atomicAdd(&cnt, 1);
        pr[p] = ((unsigned)g << 4) | (unsigned)r;   // max 2048 structurally
      }
    }
    __syncthreads();
    const int nc = cnt;
    for (int ci = 0; ci < nc; ci += 2) {
      int slot = ci + (tid >> 7);
      if (slot < nc) {
        unsigned pg = pr[slot];
        int rr  = pg & 15;
        int g   = pg >> 4;
        int row = row0 + rr;
        int col = g * 128 + (tid & 127);
        const float* xrow = x + (size_t)row * DDIM;
        const float* trow = t + (size_t)col * DDIM;
        float a = 0.0f;
        // serial k-ascending fp32 FMA chain (deterministic, exact per col)
        #pragma unroll
        for (int kq = 0; kq < DDIM; kq += 4) {
          float4 xv = *(const float4*)(xrow + kq);
          float4 tv = *(const float4*)(trow + kq);
          a = fmaf(xv.x, tv.x, a);
          a = fmaf(xv.y, tv.y, a);
          a = fmaf(xv.z, tv.z, a);
          a = fmaf(xv.w, tv.w, a);
        }
        float d2 = fmaxf(xn[row] + tn[col] - 2.0f * a, 0.0f);  // clamp = ref
        union { float f; unsigned u; } cc; cc.f = d2;
        unsigned long long pk =
            ((unsigned long long)cc.u << 32) | (unsigned)col;
        atomicMin(&best[rr], pk);
      }
    }
    __syncthreads();
  }

  if (tid < 16) {
    unsigned long long b = best[tid];
    union { unsigned u; float f; } vv; vv.u = (unsigned)(b >> 32);
    out[row0 + tid] = sqrtf(vv.f);
    out[N_ROWS + row0 + tid] = (float)(unsigned)(b & 0xffffffffu);
  }
}

// ---------------------------------------------------------------------------
// Fallback fp32 path (if ws too small) — round-1 proven
// ---------------------------------------------------------------------------
#define BM 64
#define BN 64
#define KC 16
#define S_STRIPS 32
#define PADM 68

__global__ __launch_bounds__(256) void norms_kernel_fb(
    const float* __restrict__ x, const float* __restrict__ t,
    float* __restrict__ xn, float* __restrict__ tn) {
  int wave = threadIdx.x >> 6;
  int lane = threadIdx.x & 63;
  int row  = blockIdx.x * 4 + wave;
  const float* src; float* dst;
  if (row < N_ROWS) { src = x + (size_t)row * DDIM; dst = xn + row; }
  else {
    int r = row - N_ROWS;
    if (r >= M_TGT) return;
    src = t + (size_t)r * DDIM; dst = tn + r;
  }
  float4 v = *(const float4*)(src + lane * 4);
  float s = v.x * v.x + v.y * v.y + v.z * v.z + v.w * v.w;
  #pragma unroll
  for (int off = 32; off > 0; off >>= 1) s += __shfl_xor(s, off, 64);
  if (lane == 0) *dst = s;
}

__global__ __launch_bounds__(256) void nn_main_fb(
    const float* __restrict__ x, const float* __restrict__ t,
    const float* __restrict__ xn, const float* __restrict__ tn,
    float* __restrict__ pmin, int* __restrict__ pidx) {
  __shared__ float sx[KC][PADM];
  __shared__ float st[KC][PADM];
  const int tid = threadIdx.x;
  const int rb = blockIdx.x;
  const int strip = blockIdx.y;
  const int tx = tid & 15, ty = tid >> 4;
  const int row0 = rb * BM;
  const int col_start = strip * (M_TGT / S_STRIPS);
  const int ntiles = (M_TGT / S_STRIPS) / BN;
  const int srow = tid >> 2;
  const int kq = (tid & 3) * 4;

  float runMin[4]; int runIdx[4];
  #pragma unroll
  for (int r = 0; r < 4; ++r) { runMin[r] = FLT_MAX; runIdx[r] = 0; }
  float xnr[4];
  #pragma unroll
  for (int r = 0; r < 4; ++r) xnr[r] = xn[row0 + ty * 4 + r];

  for (int tile = 0; tile < ntiles; ++tile) {
    const int cbk = col_start + tile * BN;
    float acc[4][4];
    #pragma unroll
    for (int r = 0; r < 4; ++r)
      #pragma unroll
      for (int c = 0; c < 4; ++c) acc[r][c] = 0.0f;
    #pragma unroll 1
    for (int kc = 0; kc < DDIM; kc += KC) {
      float4 xv = *(const float4*)(x + (size_t)(row0 + srow) * DDIM + kc + kq);
      float4 tv = *(const float4*)(t + (size_t)(cbk + srow) * DDIM + kc + kq);
      __syncthreads();
      sx[kq + 0][srow] = xv.x; sx[kq + 1][srow] = xv.y;
      sx[kq + 2][srow] = xv.z; sx[kq + 3][srow] = xv.w;
      st[kq + 0][srow] = tv.x; st[kq + 1][srow] = tv.y;
      st[kq + 2][srow] = tv.z; st[kq + 3][srow] = tv.w;
      __syncthreads();
      #pragma unroll
      for (int k = 0; k < KC; ++k) {
        float4 xa = *(const float4*)&sx[k][ty * 4];
        float4 tb2 = *(const float4*)&st[k][tx * 4];
        float xr[4] = {xa.x, xa.y, xa.z, xa.w};
        float tc[4] = {tb2.x, tb2.y, tb2.z, tb2.w};
        #pragma unroll
        for (int r = 0; r < 4; ++r)
          #pragma unroll
          for (int c = 0; c < 4; ++c)
            acc[r][c] = fmaf(xr[r], tc[c], acc[r][c]);
      }
    }
    #pragma unroll
    for (int r = 0; r < 4; ++r)
      #pragma unroll
      for (int c = 0; c < 4; ++c) {
        int col = cbk + tx * 4 + c;
        float d2 = xnr[r] + tn[col] - 2.0f * acc[r][c];
        if (d2 < runMin[r]) { runMin[r] = d2; runIdx[r] = col; }
      }
  }
  __syncthreads();
  float* redv = &sx[0][0];
  int*   redi = (int*)&st[0][0];
  #pragma unroll
  for (int r = 0; r < 4; ++r) {
    int lrow = ty * 4 + r;
    redv[lrow * 16 + tx] = runMin[r];
    redi[lrow * 16 + tx] = runIdx[r];
  }
  __syncthreads();
  if (tid < 64) {
    float best = FLT_MAX; int bi = 0;
    #pragma unroll
    for (int j = 0; j < 16; ++j) {
      float v = redv[tid * 16 + j];
      int   i = redi[tid * 16 + j];
      if (v < best || (v == best && i < bi)) { best = v; bi = i; }
    }
    int grow = row0 + tid;
    pmin[(size_t)grow * S_STRIPS + strip] = best;
    pidx[(size_t)grow * S_STRIPS + strip] = bi;
  }
}

__global__ __launch_bounds__(256) void reduce_final_fb(
    const float* __restrict__ pmin, const int* __restrict__ pidx,
    float* __restrict__ out) {
  int row = blockIdx.x * 256 + threadIdx.x;
  if (row >= N_ROWS) return;
  float best = FLT_MAX; int bi = 0;
  #pragma unroll 4
  for (int s = 0; s < S_STRIPS; ++s) {
    float v = pmin[(size_t)row * S_STRIPS + s];
    int   i = pidx[(size_t)row * S_STRIPS + s];
    if (v < best || (v == best && i < bi)) { best = v; bi = i; }
  }
  out[row] = sqrtf(fmaxf(best, 0.0f));
  out[N_ROWS + row] = (float)bi;
}

// ---------------------------------------------------------------------------
extern "C" void kernel_launch(void* const* d_in, const int* in_sizes, int n_in,
                              void* d_out, int out_size, void* d_ws, size_t ws_size,
                              hipStream_t stream) {
  const float* x = (const float*)d_in[0];
  const float* t = (const float*)d_in[1];
  float* ws = (float*)d_ws;
  float* out = (float*)d_out;

  float* xn = ws;                       // 4096
  float* tn = ws + N_ROWS;              // 65536

  // fast-path ws layout (floats): xn | tn | bmv[512*4096] | xb | tb
  const size_t f_bmv = (size_t)N_ROWS + M_TGT;
  const size_t f_xb  = f_bmv + (size_t)N_ROWS * NCB;
  const size_t f_tb  = f_xb + ((size_t)N_ROWS * DDIM) / 2;       // bf16 halves
  const size_t need_bytes = (f_tb + ((size_t)M_TGT * DDIM) / 2) * sizeof(float);

  if (ws_size >= need_bytes) {
    float* bmv = ws + f_bmv;
    unsigned short* xb = (unsigned short*)(ws + f_xb);
    unsigned short* tb = (unsigned short*)(ws + f_tb);

    conv_norm_all<<<(N_ROWS + M_TGT) / 4, 256, 0, stream>>>(x, t, xb, tb, xn, tn);

    nn_gemm_bf16<<<1024, 256, 0, stream>>>(xb, tb, tn, bmv);

    nn_exact<<<N_ROWS / 16, 256, 0, stream>>>(x, t, xn, tn, bmv, out);
  } else {
    norms_kernel_fb<<<(N_ROWS + M_TGT) / 4, 256, 0, stream>>>(x, t, xn, tn);
    float* pmin = ws + N_ROWS + M_TGT;
    int*   pidx = (int*)(ws + N_ROWS + M_TGT + (size_t)N_ROWS * S_STRIPS);
    dim3 grid(N_ROWS / BM, S_STRIPS);
    nn_main_fb<<<grid, 256, 0, stream>>>(x, t, xn, tn, pmin, pidx);
    reduce_final_fb<<<(N_ROWS + 255) / 256, 256, 0, stream>>>(pmin, pidx, out);
  }
}

// Round 8
// 263.221 us; speedup vs baseline: 1.9382x; 1.3703x over previous
//
#include <hip/hip_runtime.h>
#include <float.h>
#include <math.h>

#define N_ROWS 4096
#define M_TGT  65536
#define DDIM   256

// ---------------------------------------------------------------------------
// Shared types/helpers
// ---------------------------------------------------------------------------
typedef short bf16x8 __attribute__((ext_vector_type(8)));
typedef float f32x4 __attribute__((ext_vector_type(4)));
typedef unsigned short ushort4_t __attribute__((ext_vector_type(4)));

__device__ inline unsigned short f2bf(float f) {
  union { float f; unsigned u; } c; c.f = f;
  unsigned u = c.u;
  unsigned r = (u + 0x7FFFu + ((u >> 16) & 1u)) >> 16;  // RNE
  return (unsigned short)r;
}

__device__ inline void gload_lds16(const void* g, void* l) {
  __builtin_amdgcn_global_load_lds(
      (const __attribute__((address_space(1))) void*)g,
      (__attribute__((address_space(3))) void*)l, 16, 0, 0);
}

#define MFMA16(a, b, c) __builtin_amdgcn_mfma_f32_16x16x32_bf16(a, b, c, 0, 0, 0)

// ---------------------------------------------------------------------------
// Fused fp32->bf16 convert + row norm for BOTH x and t. One wave per row.
// ---------------------------------------------------------------------------
__global__ __launch_bounds__(256) void conv_norm_all(
    const float* __restrict__ x, const float* __restrict__ t,
    unsigned short* __restrict__ xb, unsigned short* __restrict__ tb,
    float* __restrict__ xn, float* __restrict__ tn) {
  int wave = threadIdx.x >> 6;
  int lane = threadIdx.x & 63;
  int row  = blockIdx.x * 4 + wave;
  const float* src;
  unsigned short* db;
  float* dn;
  if (row < N_ROWS) {
    src = x + (size_t)row * DDIM;
    db  = xb + (size_t)row * DDIM;
    dn  = xn + row;
  } else {
    int r = row - N_ROWS;
    if (r >= M_TGT) return;
    src = t + (size_t)r * DDIM;
    db  = tb + (size_t)r * DDIM;
    dn  = tn + r;
  }
  float4 v = *(const float4*)(src + lane * 4);
  float ss = v.x * v.x + v.y * v.y + v.z * v.z + v.w * v.w;
  ushort4_t o;
  o[0] = f2bf(v.x); o[1] = f2bf(v.y); o[2] = f2bf(v.z); o[3] = f2bf(v.w);
  *(ushort4_t*)(db + lane * 4) = o;
  #pragma unroll
  for (int off = 32; off > 0; off >>= 1) ss += __shfl_xor(ss, off, 64);
  if (lane == 0) *dn = ss;
}

// ---------------------------------------------------------------------------
// bf16 MFMA screening GEMM — r3-proven body, OPERAND-SWAPPED epilogue.
// 128x128 tile, 4 waves (2 t-half x 2 x-half), BK=64, single-buffered 32 KB.
// MFMA: acc[m][n] = mfma(t_frag[m], x_frag[n], acc)  -> C rows (lane-local
// cg*4+j) are TARGET columns; min-over-targets is a per-thread fmin chain
// plus 2 shfl_xor (over cg) — ~6x cheaper than the col-reduce epilogue that
// flatlined r3-r7 at 30% MfmaUtil.
// LDS layout (r3, measured 0 conflicts): 128B rows = 8 x 16B slots, phys
// slot p = s ^ (row&7); stage source pre-permuted (rule 21).
// Block order: per-XCD, row-blocks fastest -> 64KB t col-panel L2-hot.
// Output: bmv[row][cb] = min over the tile's 128 cols of (tn[col] - 2*dot).
// ---------------------------------------------------------------------------
#define GBM 128
#define GBN 128
#define GBK 64
#define NCB (M_TGT / GBN)          // 512 col tiles
#define MARGIN 1.5f

__global__ __launch_bounds__(256) void nn_gemm_bf16(
    const unsigned short* __restrict__ xb, const unsigned short* __restrict__ tb,
    const float* __restrict__ tn, float* __restrict__ bmv) {
  __shared__ __align__(16) unsigned short sX[GBM * GBK];   // 16 KB (x rows)
  __shared__ __align__(16) unsigned short sT[GBN * GBK];   // 16 KB (t rows)
  __shared__ float smin[2][128];                           // 1 KB

  const int tid  = threadIdx.x;
  const int lane = tid & 63;
  const int wid  = tid >> 6;
  const int wt   = wid >> 1;        // t half (64 cols)
  const int wx   = wid & 1;         // x half (64 rows)
  const int ln   = lane & 15;
  const int cg   = lane >> 4;

  // XCD-aware, t-panel-reuse ordering (bijective: 16384 = 8 * 32 rb * 64 cbq)
  const int bid = blockIdx.x;
  const int xcd = bid & 7;
  const int wgi = bid >> 3;
  const int rb  = wgi & 31;                  // fastest within XCD
  const int cb  = xcd * 64 + (wgi >> 5);     // 0..511
  const int row0 = rb * GBM;
  const int col0 = cb * GBN;

  // staging map (r3-proven): chunk q = i*256 + tid; row=q>>3, phys slot=q&7,
  // logical slot s = (q&7) ^ (row&7)
  int rq[4], sq[4];
  #pragma unroll
  for (int i = 0; i < 4; ++i) {
    int q = i * 256 + tid;
    rq[i] = q >> 3;
    sq[i] = (q & 7) ^ (rq[i] & 7);
  }
  char* sXc = (char*)sX;
  char* sTc = (char*)sT;

  f32x4 acc[4][4];
  const f32x4 zero = {0.0f, 0.0f, 0.0f, 0.0f};
  #pragma unroll
  for (int m = 0; m < 4; ++m)
    #pragma unroll
    for (int n = 0; n < 4; ++n) acc[m][n] = zero;

  #pragma unroll
  for (int kc = 0; kc < DDIM; kc += GBK) {
    __syncthreads();   // previous step's LDS reads complete
    #pragma unroll
    for (int i = 0; i < 4; ++i)
      gload_lds16(xb + (size_t)(row0 + rq[i]) * DDIM + kc + sq[i] * 8,
                  sXc + i * 4096 + wid * 1024);
    #pragma unroll
    for (int i = 0; i < 4; ++i)
      gload_lds16(tb + (size_t)(col0 + rq[i]) * DDIM + kc + sq[i] * 8,
                  sTc + i * 4096 + wid * 1024);
    __syncthreads();   // vmcnt(0) drained before barrier -> data ready

    bf16x8 tf[4][2], xf[4][2];
    #pragma unroll
    for (int m = 0; m < 4; ++m) {
      int r = wt * 64 + m * 16 + ln;
      #pragma unroll
      for (int kk = 0; kk < 2; ++kk) {
        int p = (kk * 4 + cg) ^ (r & 7);
        tf[m][kk] = *(const bf16x8*)(sTc + r * 128 + p * 16);
      }
    }
    #pragma unroll
    for (int n = 0; n < 4; ++n) {
      int r = wx * 64 + n * 16 + ln;
      #pragma unroll
      for (int kk = 0; kk < 2; ++kk) {
        int p = (kk * 4 + cg) ^ (r & 7);
        xf[n][kk] = *(const bf16x8*)(sXc + r * 128 + p * 16);
      }
    }
    #pragma unroll
    for (int kk = 0; kk < 2; ++kk)
      #pragma unroll
      for (int m = 0; m < 4; ++m)
        #pragma unroll
        for (int n = 0; n < 4; ++n)
          acc[m][n] = MFMA16(tf[m][kk], xf[n][kk], acc[m][n]);
  }

  // ---- epilogue: t is lane-local (C-row = cg*4+j) -> per-thread min ----
  // thread's t-cols: col0 + wt*64 + m*16 + cg*4 + j   (16 values)
  // thread's x-rows: row0 + wx*64 + n*16 + ln         (4 values)
  float tnc[4][4];
  #pragma unroll
  for (int m = 0; m < 4; ++m)
    #pragma unroll
    for (int j = 0; j < 4; ++j)
      tnc[m][j] = tn[col0 + wt * 64 + m * 16 + cg * 4 + j];

  float res[4];
  #pragma unroll
  for (int n = 0; n < 4; ++n) {
    float v = FLT_MAX;
    #pragma unroll
    for (int m = 0; m < 4; ++m)
      #pragma unroll
      for (int j = 0; j < 4; ++j)
        v = fminf(v, fmaf(-2.0f, acc[m][n][j], tnc[m][j]));
    v = fminf(v, __shfl_xor(v, 16, 64));   // reduce over cg bit 0
    v = fminf(v, __shfl_xor(v, 32, 64));   // reduce over cg bit 1
    res[n] = v;
  }

  __syncthreads();                  // all waves done with sX/sT
  if (cg == 0) {
    #pragma unroll
    for (int n = 0; n < 4; ++n)
      smin[wt][wx * 64 + n * 16 + ln] = res[n];
  }
  __syncthreads();
  if (tid < 128)
    bmv[(size_t)(row0 + tid) * NCB + cb] = fminf(smin[0][tid], smin[1][tid]);
}

// ---------------------------------------------------------------------------
// Per-row candidate selection + exact fp32 verification (r3-proven).
// One block per row; verify 2 candidate tiles concurrently (128 thr each).
// ---------------------------------------------------------------------------
__global__ __launch_bounds__(256) void nn_exact(
    const float* __restrict__ x, const float* __restrict__ t,
    const float* __restrict__ xn, const float* __restrict__ tn,
    const float* __restrict__ bmv, float* __restrict__ out) {
  __shared__ float sv[NCB];
  __shared__ int   clist[NCB];
  __shared__ int   cnt;
  __shared__ float wmin[4];
  __shared__ float rv[256];
  __shared__ int   ri[256];

  const int row = blockIdx.x;
  const int tid = threadIdx.x;

  if (tid == 0) cnt = 0;
  float lmin = FLT_MAX;
  #pragma unroll
  for (int e = tid; e < NCB; e += 256) {
    float v = bmv[(size_t)row * NCB + e];
    sv[e] = v;
    lmin = fminf(lmin, v);
  }
  #pragma unroll
  for (int off = 32; off > 0; off >>= 1) lmin = fminf(lmin, __shfl_xor(lmin, off, 64));
  if ((tid & 63) == 0) wmin[tid >> 6] = lmin;
  __syncthreads();
  const float g = fminf(fminf(wmin[0], wmin[1]), fminf(wmin[2], wmin[3]));

  #pragma unroll
  for (int e = tid; e < NCB; e += 256) {
    if (sv[e] <= g + MARGIN) {
      int p = atomicAdd(&cnt, 1);
      clist[p] = e;
    }
  }
  __syncthreads();
  const int nc = cnt;

  float best = FLT_MAX;
  int   bidx = 0x7FFFFFFF;
  const float xnr = xn[row];
  const float* xrow = x + (size_t)row * DDIM;

  for (int ci = 0; ci < nc; ci += 2) {
    int slot = ci + (tid >> 7);
    if (slot < nc) {
      int col = clist[slot] * 128 + (tid & 127);
      const float* trow = t + (size_t)col * DDIM;
      float acc = 0.0f;
      // serial k-ascending fp32 FMA chain (deterministic, exact per col)
      for (int kq = 0; kq < DDIM; kq += 4) {
        float4 xv = *(const float4*)(xrow + kq);
        float4 tv = *(const float4*)(trow + kq);
        acc = fmaf(xv.x, tv.x, acc);
        acc = fmaf(xv.y, tv.y, acc);
        acc = fmaf(xv.z, tv.z, acc);
        acc = fmaf(xv.w, tv.w, acc);
      }
      float d2 = xnr + tn[col] - 2.0f * acc;
      if (d2 < best || (d2 == best && col < bidx)) { best = d2; bidx = col; }
    }
  }
  rv[tid] = best; ri[tid] = bidx;
  __syncthreads();
  for (int s = 128; s >= 1; s >>= 1) {
    if (tid < s) {
      float vo = rv[tid + s]; int io = ri[tid + s];
      if (vo < rv[tid] || (vo == rv[tid] && io < ri[tid])) { rv[tid] = vo; ri[tid] = io; }
    }
    __syncthreads();
  }
  if (tid == 0) {
    out[row] = sqrtf(fmaxf(rv[0], 0.0f));
    out[N_ROWS + row] = (float)ri[0];
  }
}

// ---------------------------------------------------------------------------
// Fallback fp32 path (if ws too small) — round-1 proven
// ---------------------------------------------------------------------------
#define BM 64
#define BN 64
#define KC 16
#define S_STRIPS 32
#define PADM 68

__global__ __launch_bounds__(256) void norms_kernel_fb(
    const float* __restrict__ x, const float* __restrict__ t,
    float* __restrict__ xn, float* __restrict__ tn) {
  int wave = threadIdx.x >> 6;
  int lane = threadIdx.x & 63;
  int row  = blockIdx.x * 4 + wave;
  const float* src; float* dst;
  if (row < N_ROWS) { src = x + (size_t)row * DDIM; dst = xn + row; }
  else {
    int r = row - N_ROWS;
    if (r >= M_TGT) return;
    src = t + (size_t)r * DDIM; dst = tn + r;
  }
  float4 v = *(const float4*)(src + lane * 4);
  float s = v.x * v.x + v.y * v.y + v.z * v.z + v.w * v.w;
  #pragma unroll
  for (int off = 32; off > 0; off >>= 1) s += __shfl_xor(s, off, 64);
  if (lane == 0) *dst = s;
}

__global__ __launch_bounds__(256) void nn_main_fb(
    const float* __restrict__ x, const float* __restrict__ t,
    const float* __restrict__ xn, const float* __restrict__ tn,
    float* __restrict__ pmin, int* __restrict__ pidx) {
  __shared__ float sx[KC][PADM];
  __shared__ float st[KC][PADM];
  const int tid = threadIdx.x;
  const int rb = blockIdx.x;
  const int strip = blockIdx.y;
  const int tx = tid & 15, ty = tid >> 4;
  const int row0 = rb * BM;
  const int col_start = strip * (M_TGT / S_STRIPS);
  const int ntiles = (M_TGT / S_STRIPS) / BN;
  const int srow = tid >> 2;
  const int kq = (tid & 3) * 4;

  float runMin[4]; int runIdx[4];
  #pragma unroll
  for (int r = 0; r < 4; ++r) { runMin[r] = FLT_MAX; runIdx[r] = 0; }
  float xnr[4];
  #pragma unroll
  for (int r = 0; r < 4; ++r) xnr[r] = xn[row0 + ty * 4 + r];

  for (int tile = 0; tile < ntiles; ++tile) {
    const int cbk = col_start + tile * BN;
    float acc[4][4];
    #pragma unroll
    for (int r = 0; r < 4; ++r)
      #pragma unroll
      for (int c = 0; c < 4; ++c) acc[r][c] = 0.0f;
    #pragma unroll 1
    for (int kc = 0; kc < DDIM; kc += KC) {
      float4 xv = *(const float4*)(x + (size_t)(row0 + srow) * DDIM + kc + kq);
      float4 tv = *(const float4*)(t + (size_t)(cbk + srow) * DDIM + kc + kq);
      __syncthreads();
      sx[kq + 0][srow] = xv.x; sx[kq + 1][srow] = xv.y;
      sx[kq + 2][srow] = xv.z; sx[kq + 3][srow] = xv.w;
      st[kq + 0][srow] = tv.x; st[kq + 1][srow] = tv.y;
      st[kq + 2][srow] = tv.z; st[kq + 3][srow] = tv.w;
      __syncthreads();
      #pragma unroll
      for (int k = 0; k < KC; ++k) {
        float4 xa = *(const float4*)&sx[k][ty * 4];
        float4 tb2 = *(const float4*)&st[k][tx * 4];
        float xr[4] = {xa.x, xa.y, xa.z, xa.w};
        float tc[4] = {tb2.x, tb2.y, tb2.z, tb2.w};
        #pragma unroll
        for (int r = 0; r < 4; ++r)
          #pragma unroll
          for (int c = 0; c < 4; ++c)
            acc[r][c] = fmaf(xr[r], tc[c], acc[r][c]);
      }
    }
    #pragma unroll
    for (int r = 0; r < 4; ++r)
      #pragma unroll
      for (int c = 0; c < 4; ++c) {
        int col = cbk + tx * 4 + c;
        float d2 = xnr[r] + tn[col] - 2.0f * acc[r][c];
        if (d2 < runMin[r]) { runMin[r] = d2; runIdx[r] = col; }
      }
  }
  __syncthreads();
  float* redv = &sx[0][0];
  int*   redi = (int*)&st[0][0];
  #pragma unroll
  for (int r = 0; r < 4; ++r) {
    int lrow = ty * 4 + r;
    redv[lrow * 16 + tx] = runMin[r];
    redi[lrow * 16 + tx] = runIdx[r];
  }
  __syncthreads();
  if (tid < 64) {
    float best = FLT_MAX; int bi = 0;
    #pragma unroll
    for (int j = 0; j < 16; ++j) {
      float v = redv[tid * 16 + j];
      int   i = redi[tid * 16 + j];
      if (v < best || (v == best && i < bi)) { best = v; bi = i; }
    }
    int grow = row0 + tid;
    pmin[(size_t)grow * S_STRIPS + strip] = best;
    pidx[(size_t)grow * S_STRIPS + strip] = bi;
  }
}

__global__ __launch_bounds__(256) void reduce_final_fb(
    const float* __restrict__ pmin, const int* __restrict__ pidx,
    float* __restrict__ out) {
  int row = blockIdx.x * 256 + threadIdx.x;
  if (row >= N_ROWS) return;
  float best = FLT_MAX; int bi = 0;
  #pragma unroll 4
  for (int s = 0; s < S_STRIPS; ++s) {
    float v = pmin[(size_t)row * S_STRIPS + s];
    int   i = pidx[(size_t)row * S_STRIPS + s];
    if (v < best || (v == best && i < bi)) { best = v; bi = i; }
  }
  out[row] = sqrtf(fmaxf(best, 0.0f));
  out[N_ROWS + row] = (float)bi;
}

// ---------------------------------------------------------------------------
extern "C" void kernel_launch(void* const* d_in, const int* in_sizes, int n_in,
                              void* d_out, int out_size, void* d_ws, size_t ws_size,
                              hipStream_t stream) {
  const float* x = (const float*)d_in[0];
  const float* t = (const float*)d_in[1];
  float* ws = (float*)d_ws;
  float* out = (float*)d_out;

  float* xn = ws;                       // 4096
  float* tn = ws + N_ROWS;              // 65536

  // fast-path ws layout (floats): xn | tn | bmv[4096*512] | xb | tb
  const size_t f_bmv = (size_t)N_ROWS + M_TGT;
  const size_t f_xb  = f_bmv + (size_t)N_ROWS * NCB;
  const size_t f_tb  = f_xb + ((size_t)N_ROWS * DDIM) / 2;       // bf16 halves
  const size_t need_bytes = (f_tb + ((size_t)M_TGT * DDIM) / 2) * sizeof(float);

  if (ws_size >= need_bytes) {
    float* bmv = ws + f_bmv;
    unsigned short* xb = (unsigned short*)(ws + f_xb);
    unsigned short* tb = (unsigned short*)(ws + f_tb);

    conv_norm_all<<<(N_ROWS + M_TGT) / 4, 256, 0, stream>>>(x, t, xb, tb, xn, tn);

    nn_gemm_bf16<<<(N_ROWS / GBM) * NCB, 256, 0, stream>>>(xb, tb, tn, bmv);

    nn_exact<<<N_ROWS, 256, 0, stream>>>(x, t, xn, tn, bmv, out);
  } else {
    norms_kernel_fb<<<(N_ROWS + M_TGT) / 4, 256, 0, stream>>>(x, t, xn, tn);
    float* pmin = ws + N_ROWS + M_TGT;
    int*   pidx = (int*)(ws + N_ROWS + M_TGT + (size_t)N_ROWS * S_STRIPS);
    dim3 grid(N_ROWS / BM, S_STRIPS);
    nn_main_fb<<<grid, 256, 0, stream>>>(x, t, xn, tn, pmin, pidx);
    reduce_final_fb<<<(N_ROWS + 255) / 256, 256, 0, stream>>>(pmin, pidx, out);
  }
}

// Round 9
// 201.311 us; speedup vs baseline: 2.5343x; 1.3075x over previous
//
#include <hip/hip_runtime.h>
#include <float.h>
#include <math.h>

#define N_ROWS 4096
#define M_TGT  65536
#define DDIM   256

// ---------------------------------------------------------------------------
// Shared types/helpers
// ---------------------------------------------------------------------------
typedef short bf16x8 __attribute__((ext_vector_type(8)));
typedef float f32x4 __attribute__((ext_vector_type(4)));
typedef unsigned short ushort4_t __attribute__((ext_vector_type(4)));

__device__ inline unsigned short f2bf(float f) {
  union { float f; unsigned u; } c; c.f = f;
  unsigned u = c.u;
  unsigned r = (u + 0x7FFFu + ((u >> 16) & 1u)) >> 16;  // RNE
  return (unsigned short)r;
}

__device__ inline void gload_lds16(const void* g, void* l) {
  __builtin_amdgcn_global_load_lds(
      (const __attribute__((address_space(1))) void*)g,
      (__attribute__((address_space(3))) void*)l, 16, 0, 0);
}

#define MFMA16(a, b, c) __builtin_amdgcn_mfma_f32_16x16x32_bf16(a, b, c, 0, 0, 0)

// ---------------------------------------------------------------------------
// Fused fp32->bf16 convert + row norm for BOTH x and t. One wave per row.
// ---------------------------------------------------------------------------
__global__ __launch_bounds__(256) void conv_norm_all(
    const float* __restrict__ x, const float* __restrict__ t,
    unsigned short* __restrict__ xb, unsigned short* __restrict__ tb,
    float* __restrict__ xn, float* __restrict__ tn) {
  int wave = threadIdx.x >> 6;
  int lane = threadIdx.x & 63;
  int row  = blockIdx.x * 4 + wave;
  const float* src;
  unsigned short* db;
  float* dn;
  if (row < N_ROWS) {
    src = x + (size_t)row * DDIM;
    db  = xb + (size_t)row * DDIM;
    dn  = xn + row;
  } else {
    int r = row - N_ROWS;
    if (r >= M_TGT) return;
    src = t + (size_t)r * DDIM;
    db  = tb + (size_t)r * DDIM;
    dn  = tn + r;
  }
  float4 v = *(const float4*)(src + lane * 4);
  float ss = v.x * v.x + v.y * v.y + v.z * v.z + v.w * v.w;
  ushort4_t o;
  o[0] = f2bf(v.x); o[1] = f2bf(v.y); o[2] = f2bf(v.z); o[3] = f2bf(v.w);
  *(ushort4_t*)(db + lane * 4) = o;
  #pragma unroll
  for (int off = 32; off > 0; off >>= 1) ss += __shfl_xor(ss, off, 64);
  if (lane == 0) *dn = ss;
}

// ---------------------------------------------------------------------------
// bf16 MFMA screening GEMM — r8-proven body (128x128, BK=64, operand-swapped
// epilogue, 0-conflict XOR LDS), now with FINE 32-col group mins.
// C-rows (lane-local cg*4+j) are TARGET cols; a thread's 16 t-cols split by
// m-pair into two 32-col groups -> per-group min = per-thread fmin chain +
// 2 shfl_xor. Output: bmv32[row][2048] (4 groups per 128-col tile).
// Per-block global write-back unchanged (same 64B lines as r8).
// ---------------------------------------------------------------------------
#define GBM 128
#define GBN 128
#define GBK 64
#define NCB 512                    // 128-col tiles
#define NGRP 2048                  // 32-col groups
#define MARGIN 1.5f

__global__ __launch_bounds__(256) void nn_gemm_bf16(
    const unsigned short* __restrict__ xb, const unsigned short* __restrict__ tb,
    const float* __restrict__ tn, float* __restrict__ bmv32) {
  __shared__ __align__(16) unsigned short sX[GBM * GBK];   // 16 KB (x rows)
  __shared__ __align__(16) unsigned short sT[GBN * GBK];   // 16 KB (t rows)
  __shared__ float smin[4][128];                           // 2 KB

  const int tid  = threadIdx.x;
  const int lane = tid & 63;
  const int wid  = tid >> 6;
  const int wt   = wid >> 1;        // t half (64 cols)
  const int wx   = wid & 1;         // x half (64 rows)
  const int ln   = lane & 15;
  const int cg   = lane >> 4;

  // XCD-aware, t-panel-reuse ordering (bijective: 16384 = 8 * 32 rb * 64 cbq)
  const int bid = blockIdx.x;
  const int xcd = bid & 7;
  const int wgi = bid >> 3;
  const int rb  = wgi & 31;                  // fastest within XCD
  const int cb  = xcd * 64 + (wgi >> 5);     // 0..511
  const int row0 = rb * GBM;
  const int col0 = cb * GBN;

  // staging map (r3-proven): chunk q = i*256 + tid; row=q>>3, phys slot=q&7,
  // logical slot s = (q&7) ^ (row&7)
  int rq[4], sq[4];
  #pragma unroll
  for (int i = 0; i < 4; ++i) {
    int q = i * 256 + tid;
    rq[i] = q >> 3;
    sq[i] = (q & 7) ^ (rq[i] & 7);
  }
  char* sXc = (char*)sX;
  char* sTc = (char*)sT;

  f32x4 acc[4][4];
  const f32x4 zero = {0.0f, 0.0f, 0.0f, 0.0f};
  #pragma unroll
  for (int m = 0; m < 4; ++m)
    #pragma unroll
    for (int n = 0; n < 4; ++n) acc[m][n] = zero;

  #pragma unroll
  for (int kc = 0; kc < DDIM; kc += GBK) {
    __syncthreads();   // previous step's LDS reads complete
    #pragma unroll
    for (int i = 0; i < 4; ++i)
      gload_lds16(xb + (size_t)(row0 + rq[i]) * DDIM + kc + sq[i] * 8,
                  sXc + i * 4096 + wid * 1024);
    #pragma unroll
    for (int i = 0; i < 4; ++i)
      gload_lds16(tb + (size_t)(col0 + rq[i]) * DDIM + kc + sq[i] * 8,
                  sTc + i * 4096 + wid * 1024);
    __syncthreads();   // vmcnt(0) drained before barrier -> data ready

    bf16x8 tf[4][2], xf[4][2];
    #pragma unroll
    for (int m = 0; m < 4; ++m) {
      int r = wt * 64 + m * 16 + ln;
      #pragma unroll
      for (int kk = 0; kk < 2; ++kk) {
        int p = (kk * 4 + cg) ^ (r & 7);
        tf[m][kk] = *(const bf16x8*)(sTc + r * 128 + p * 16);
      }
    }
    #pragma unroll
    for (int n = 0; n < 4; ++n) {
      int r = wx * 64 + n * 16 + ln;
      #pragma unroll
      for (int kk = 0; kk < 2; ++kk) {
        int p = (kk * 4 + cg) ^ (r & 7);
        xf[n][kk] = *(const bf16x8*)(sXc + r * 128 + p * 16);
      }
    }
    #pragma unroll
    for (int kk = 0; kk < 2; ++kk)
      #pragma unroll
      for (int m = 0; m < 4; ++m)
        #pragma unroll
        for (int n = 0; n < 4; ++n)
          acc[m][n] = MFMA16(tf[m][kk], xf[n][kk], acc[m][n]);
  }

  // ---- epilogue: per-thread min per 32-col group (m-pair), per x-row ----
  float tnc[4][4];
  #pragma unroll
  for (int m = 0; m < 4; ++m)
    #pragma unroll
    for (int j = 0; j < 4; ++j)
      tnc[m][j] = tn[col0 + wt * 64 + m * 16 + cg * 4 + j];

  float vres[2][4];
  #pragma unroll
  for (int mh2 = 0; mh2 < 2; ++mh2) {
    #pragma unroll
    for (int n = 0; n < 4; ++n) {
      float v = FLT_MAX;
      #pragma unroll
      for (int mi = 0; mi < 2; ++mi) {
        int m = mh2 * 2 + mi;
        #pragma unroll
        for (int j = 0; j < 4; ++j)
          v = fminf(v, fmaf(-2.0f, acc[m][n][j], tnc[m][j]));
      }
      v = fminf(v, __shfl_xor(v, 16, 64));   // reduce over cg bit 0
      v = fminf(v, __shfl_xor(v, 32, 64));   // reduce over cg bit 1
      vres[mh2][n] = v;
    }
  }

  __syncthreads();                  // all waves done with sX/sT
  if (cg == 0) {
    #pragma unroll
    for (int mh2 = 0; mh2 < 2; ++mh2)
      #pragma unroll
      for (int n = 0; n < 4; ++n)
        smin[wt * 2 + mh2][wx * 64 + n * 16 + ln] = vres[mh2][n];
  }
  __syncthreads();
  if (tid < 128) {
    float4 o;
    o.x = smin[0][tid]; o.y = smin[1][tid];
    o.z = smin[2][tid]; o.w = smin[3][tid];
    *(float4*)&bmv32[(size_t)(row0 + tid) * NGRP + (size_t)cb * 4] = o;
  }
}

// ---------------------------------------------------------------------------
// Fine candidate selection + exact fp32 verification. One block per row.
// Scan 2048 group-mins (8 KB contiguous), verify candidate 32-col groups
// (8 groups per pass, 32 threads each).
// ---------------------------------------------------------------------------
__global__ __launch_bounds__(256) void nn_exact_fine(
    const float* __restrict__ x, const float* __restrict__ t,
    const float* __restrict__ xn, const float* __restrict__ tn,
    const float* __restrict__ bmv32, float* __restrict__ out) {
  __shared__ float wmin[4];
  __shared__ int   clist[NGRP];
  __shared__ int   cnt;
  __shared__ float rv[256];
  __shared__ int   ri[256];

  const int row = blockIdx.x;
  const int tid = threadIdx.x;
  const float* brow = bmv32 + (size_t)row * NGRP;

  if (tid == 0) cnt = 0;
  float4 v0 = *(const float4*)(brow + tid * 8);
  float4 v1 = *(const float4*)(brow + tid * 8 + 4);
  float lmin = fminf(fminf(fminf(v0.x, v0.y), fminf(v0.z, v0.w)),
                     fminf(fminf(v1.x, v1.y), fminf(v1.z, v1.w)));
  #pragma unroll
  for (int off = 32; off > 0; off >>= 1)
    lmin = fminf(lmin, __shfl_xor(lmin, off, 64));
  if ((tid & 63) == 0) wmin[tid >> 6] = lmin;
  __syncthreads();
  const float thr =
      fminf(fminf(wmin[0], wmin[1]), fminf(wmin[2], wmin[3])) + MARGIN;

  {
    float vv[8] = {v0.x, v0.y, v0.z, v0.w, v1.x, v1.y, v1.z, v1.w};
    #pragma unroll
    for (int k = 0; k < 8; ++k) {
      if (vv[k] <= thr) {
        int p = atomicAdd(&cnt, 1);
        clist[p] = tid * 8 + k;
      }
    }
  }
  __syncthreads();
  const int nc = cnt;

  float best = FLT_MAX;
  int   bidx = 0x7FFFFFFF;
  const float xnr = xn[row];
  const float* xrow = x + (size_t)row * DDIM;

  for (int ci = 0; ci < nc; ci += 8) {
    int slot = ci + (tid >> 5);
    if (slot < nc) {
      int col = clist[slot] * 32 + (tid & 31);
      const float* trow = t + (size_t)col * DDIM;
      float acc = 0.0f;
      // serial k-ascending fp32 FMA chain (deterministic, exact per col)
      for (int kq = 0; kq < DDIM; kq += 4) {
        float4 xv = *(const float4*)(xrow + kq);
        float4 tv = *(const float4*)(trow + kq);
        acc = fmaf(xv.x, tv.x, acc);
        acc = fmaf(xv.y, tv.y, acc);
        acc = fmaf(xv.z, tv.z, acc);
        acc = fmaf(xv.w, tv.w, acc);
      }
      float d2 = xnr + tn[col] - 2.0f * acc;
      if (d2 < best || (d2 == best && col < bidx)) { best = d2; bidx = col; }
    }
  }
  rv[tid] = best; ri[tid] = bidx;
  __syncthreads();
  for (int s = 128; s >= 1; s >>= 1) {
    if (tid < s) {
      float vo = rv[tid + s]; int io = ri[tid + s];
      if (vo < rv[tid] || (vo == rv[tid] && io < ri[tid])) { rv[tid] = vo; ri[tid] = io; }
    }
    __syncthreads();
  }
  if (tid == 0) {
    out[row] = sqrtf(fmaxf(rv[0], 0.0f));
    out[N_ROWS + row] = (float)ri[0];
  }
}

// ---------------------------------------------------------------------------
// MIDDLE path (ws too small for bmv32): r8-proven coarse GEMM + exact.
// ---------------------------------------------------------------------------
__global__ __launch_bounds__(256) void nn_gemm_mid(
    const unsigned short* __restrict__ xb, const unsigned short* __restrict__ tb,
    const float* __restrict__ tn, float* __restrict__ bmv) {
  __shared__ __align__(16) unsigned short sX[GBM * GBK];
  __shared__ __align__(16) unsigned short sT[GBN * GBK];
  __shared__ float smin[2][128];

  const int tid  = threadIdx.x;
  const int lane = tid & 63;
  const int wid  = tid >> 6;
  const int wt   = wid >> 1;
  const int wx   = wid & 1;
  const int ln   = lane & 15;
  const int cg   = lane >> 4;

  const int bid = blockIdx.x;
  const int xcd = bid & 7;
  const int wgi = bid >> 3;
  const int rb  = wgi & 31;
  const int cb  = xcd * 64 + (wgi >> 5);
  const int row0 = rb * GBM;
  const int col0 = cb * GBN;

  int rq[4], sq[4];
  #pragma unroll
  for (int i = 0; i < 4; ++i) {
    int q = i * 256 + tid;
    rq[i] = q >> 3;
    sq[i] = (q & 7) ^ (rq[i] & 7);
  }
  char* sXc = (char*)sX;
  char* sTc = (char*)sT;

  f32x4 acc[4][4];
  const f32x4 zero = {0.0f, 0.0f, 0.0f, 0.0f};
  #pragma unroll
  for (int m = 0; m < 4; ++m)
    #pragma unroll
    for (int n = 0; n < 4; ++n) acc[m][n] = zero;

  #pragma unroll
  for (int kc = 0; kc < DDIM; kc += GBK) {
    __syncthreads();
    #pragma unroll
    for (int i = 0; i < 4; ++i)
      gload_lds16(xb + (size_t)(row0 + rq[i]) * DDIM + kc + sq[i] * 8,
                  sXc + i * 4096 + wid * 1024);
    #pragma unroll
    for (int i = 0; i < 4; ++i)
      gload_lds16(tb + (size_t)(col0 + rq[i]) * DDIM + kc + sq[i] * 8,
                  sTc + i * 4096 + wid * 1024);
    __syncthreads();

    bf16x8 tf[4][2], xf[4][2];
    #pragma unroll
    for (int m = 0; m < 4; ++m) {
      int r = wt * 64 + m * 16 + ln;
      #pragma unroll
      for (int kk = 0; kk < 2; ++kk) {
        int p = (kk * 4 + cg) ^ (r & 7);
        tf[m][kk] = *(const bf16x8*)(sTc + r * 128 + p * 16);
      }
    }
    #pragma unroll
    for (int n = 0; n < 4; ++n) {
      int r = wx * 64 + n * 16 + ln;
      #pragma unroll
      for (int kk = 0; kk < 2; ++kk) {
        int p = (kk * 4 + cg) ^ (r & 7);
        xf[n][kk] = *(const bf16x8*)(sXc + r * 128 + p * 16);
      }
    }
    #pragma unroll
    for (int kk = 0; kk < 2; ++kk)
      #pragma unroll
      for (int m = 0; m < 4; ++m)
        #pragma unroll
        for (int n = 0; n < 4; ++n)
          acc[m][n] = MFMA16(tf[m][kk], xf[n][kk], acc[m][n]);
  }

  float tnc[4][4];
  #pragma unroll
  for (int m = 0; m < 4; ++m)
    #pragma unroll
    for (int j = 0; j < 4; ++j)
      tnc[m][j] = tn[col0 + wt * 64 + m * 16 + cg * 4 + j];

  float res[4];
  #pragma unroll
  for (int n = 0; n < 4; ++n) {
    float v = FLT_MAX;
    #pragma unroll
    for (int m = 0; m < 4; ++m)
      #pragma unroll
      for (int j = 0; j < 4; ++j)
        v = fminf(v, fmaf(-2.0f, acc[m][n][j], tnc[m][j]));
    v = fminf(v, __shfl_xor(v, 16, 64));
    v = fminf(v, __shfl_xor(v, 32, 64));
    res[n] = v;
  }

  __syncthreads();
  if (cg == 0) {
    #pragma unroll
    for (int n = 0; n < 4; ++n)
      smin[wt][wx * 64 + n * 16 + ln] = res[n];
  }
  __syncthreads();
  if (tid < 128)
    bmv[(size_t)(row0 + tid) * NCB + cb] = fminf(smin[0][tid], smin[1][tid]);
}

__global__ __launch_bounds__(256) void nn_exact_mid(
    const float* __restrict__ x, const float* __restrict__ t,
    const float* __restrict__ xn, const float* __restrict__ tn,
    const float* __restrict__ bmv, float* __restrict__ out) {
  __shared__ float sv[NCB];
  __shared__ int   clist[NCB];
  __shared__ int   cnt;
  __shared__ float wmin[4];
  __shared__ float rv[256];
  __shared__ int   ri[256];

  const int row = blockIdx.x;
  const int tid = threadIdx.x;

  if (tid == 0) cnt = 0;
  float lmin = FLT_MAX;
  #pragma unroll
  for (int e = tid; e < NCB; e += 256) {
    float v = bmv[(size_t)row * NCB + e];
    sv[e] = v;
    lmin = fminf(lmin, v);
  }
  #pragma unroll
  for (int off = 32; off > 0; off >>= 1) lmin = fminf(lmin, __shfl_xor(lmin, off, 64));
  if ((tid & 63) == 0) wmin[tid >> 6] = lmin;
  __syncthreads();
  const float g = fminf(fminf(wmin[0], wmin[1]), fminf(wmin[2], wmin[3]));

  #pragma unroll
  for (int e = tid; e < NCB; e += 256) {
    if (sv[e] <= g + MARGIN) {
      int p = atomicAdd(&cnt, 1);
      clist[p] = e;
    }
  }
  __syncthreads();
  const int nc = cnt;

  float best = FLT_MAX;
  int   bidx = 0x7FFFFFFF;
  const float xnr = xn[row];
  const float* xrow = x + (size_t)row * DDIM;

  for (int ci = 0; ci < nc; ci += 2) {
    int slot = ci + (tid >> 7);
    if (slot < nc) {
      int col = clist[slot] * 128 + (tid & 127);
      const float* trow = t + (size_t)col * DDIM;
      float acc = 0.0f;
      for (int kq = 0; kq < DDIM; kq += 4) {
        float4 xv = *(const float4*)(xrow + kq);
        float4 tv = *(const float4*)(trow + kq);
        acc = fmaf(xv.x, tv.x, acc);
        acc = fmaf(xv.y, tv.y, acc);
        acc = fmaf(xv.z, tv.z, acc);
        acc = fmaf(xv.w, tv.w, acc);
      }
      float d2 = xnr + tn[col] - 2.0f * acc;
      if (d2 < best || (d2 == best && col < bidx)) { best = d2; bidx = col; }
    }
  }
  rv[tid] = best; ri[tid] = bidx;
  __syncthreads();
  for (int s = 128; s >= 1; s >>= 1) {
    if (tid < s) {
      float vo = rv[tid + s]; int io = ri[tid + s];
      if (vo < rv[tid] || (vo == rv[tid] && io < ri[tid])) { rv[tid] = vo; ri[tid] = io; }
    }
    __syncthreads();
  }
  if (tid == 0) {
    out[row] = sqrtf(fmaxf(rv[0], 0.0f));
    out[N_ROWS + row] = (float)ri[0];
  }
}

// ---------------------------------------------------------------------------
// Fallback fp32 path (if ws tiny) — round-1 proven
// ---------------------------------------------------------------------------
#define BM 64
#define BN 64
#define KC 16
#define S_STRIPS 32
#define PADM 68

__global__ __launch_bounds__(256) void norms_kernel_fb(
    const float* __restrict__ x, const float* __restrict__ t,
    float* __restrict__ xn, float* __restrict__ tn) {
  int wave = threadIdx.x >> 6;
  int lane = threadIdx.x & 63;
  int row  = blockIdx.x * 4 + wave;
  const float* src; float* dst;
  if (row < N_ROWS) { src = x + (size_t)row * DDIM; dst = xn + row; }
  else {
    int r = row - N_ROWS;
    if (r >= M_TGT) return;
    src = t + (size_t)r * DDIM; dst = tn + r;
  }
  float4 v = *(const float4*)(src + lane * 4);
  float s = v.x * v.x + v.y * v.y + v.z * v.z + v.w * v.w;
  #pragma unroll
  for (int off = 32; off > 0; off >>= 1) s += __shfl_xor(s, off, 64);
  if (lane == 0) *dst = s;
}

__global__ __launch_bounds__(256) void nn_main_fb(
    const float* __restrict__ x, const float* __restrict__ t,
    const float* __restrict__ xn, const float* __restrict__ tn,
    float* __restrict__ pmin, int* __restrict__ pidx) {
  __shared__ float sx[KC][PADM];
  __shared__ float st[KC][PADM];
  const int tid = threadIdx.x;
  const int rb = blockIdx.x;
  const int strip = blockIdx.y;
  const int tx = tid & 15, ty = tid >> 4;
  const int row0 = rb * BM;
  const int col_start = strip * (M_TGT / S_STRIPS);
  const int ntiles = (M_TGT / S_STRIPS) / BN;
  const int srow = tid >> 2;
  const int kq = (tid & 3) * 4;

  float runMin[4]; int runIdx[4];
  #pragma unroll
  for (int r = 0; r < 4; ++r) { runMin[r] = FLT_MAX; runIdx[r] = 0; }
  float xnr[4];
  #pragma unroll
  for (int r = 0; r < 4; ++r) xnr[r] = xn[row0 + ty * 4 + r];

  for (int tile = 0; tile < ntiles; ++tile) {
    const int cbk = col_start + tile * BN;
    float acc[4][4];
    #pragma unroll
    for (int r = 0; r < 4; ++r)
      #pragma unroll
      for (int c = 0; c < 4; ++c) acc[r][c] = 0.0f;
    #pragma unroll 1
    for (int kc = 0; kc < DDIM; kc += KC) {
      float4 xv = *(const float4*)(x + (size_t)(row0 + srow) * DDIM + kc + kq);
      float4 tv = *(const float4*)(t + (size_t)(cbk + srow) * DDIM + kc + kq);
      __syncthreads();
      sx[kq + 0][srow] = xv.x; sx[kq + 1][srow] = xv.y;
      sx[kq + 2][srow] = xv.z; sx[kq + 3][srow] = xv.w;
      st[kq + 0][srow] = tv.x; st[kq + 1][srow] = tv.y;
      st[kq + 2][srow] = tv.z; st[kq + 3][srow] = tv.w;
      __syncthreads();
      #pragma unroll
      for (int k = 0; k < KC; ++k) {
        float4 xa = *(const float4*)&sx[k][ty * 4];
        float4 tb2 = *(const float4*)&st[k][tx * 4];
        float xr[4] = {xa.x, xa.y, xa.z, xa.w};
        float tc[4] = {tb2.x, tb2.y, tb2.z, tb2.w};
        #pragma unroll
        for (int r = 0; r < 4; ++r)
          #pragma unroll
          for (int c = 0; c < 4; ++c)
            acc[r][c] = fmaf(xr[r], tc[c], acc[r][c]);
      }
    }
    #pragma unroll
    for (int r = 0; r < 4; ++r)
      #pragma unroll
      for (int c = 0; c < 4; ++c) {
        int col = cbk + tx * 4 + c;
        float d2 = xnr[r] + tn[col] - 2.0f * acc[r][c];
        if (d2 < runMin[r]) { runMin[r] = d2; runIdx[r] = col; }
      }
  }
  __syncthreads();
  float* redv = &sx[0][0];
  int*   redi = (int*)&st[0][0];
  #pragma unroll
  for (int r = 0; r < 4; ++r) {
    int lrow = ty * 4 + r;
    redv[lrow * 16 + tx] = runMin[r];
    redi[lrow * 16 + tx] = runIdx[r];
  }
  __syncthreads();
  if (tid < 64) {
    float best = FLT_MAX; int bi = 0;
    #pragma unroll
    for (int j = 0; j < 16; ++j) {
      float v = redv[tid * 16 + j];
      int   i = redi[tid * 16 + j];
      if (v < best || (v == best && i < bi)) { best = v; bi = i; }
    }
    int grow = row0 + tid;
    pmin[(size_t)grow * S_STRIPS + strip] = best;
    pidx[(size_t)grow * S_STRIPS + strip] = bi;
  }
}

__global__ __launch_bounds__(256) void reduce_final_fb(
    const float* __restrict__ pmin, const int* __restrict__ pidx,
    float* __restrict__ out) {
  int row = blockIdx.x * 256 + threadIdx.x;
  if (row >= N_ROWS) return;
  float best = FLT_MAX; int bi = 0;
  #pragma unroll 4
  for (int s = 0; s < S_STRIPS; ++s) {
    float v = pmin[(size_t)row * S_STRIPS + s];
    int   i = pidx[(size_t)row * S_STRIPS + s];
    if (v < best || (v == best && i < bi)) { best = v; bi = i; }
  }
  out[row] = sqrtf(fmaxf(best, 0.0f));
  out[N_ROWS + row] = (float)bi;
}

// ---------------------------------------------------------------------------
extern "C" void kernel_launch(void* const* d_in, const int* in_sizes, int n_in,
                              void* d_out, int out_size, void* d_ws, size_t ws_size,
                              hipStream_t stream) {
  const float* x = (const float*)d_in[0];
  const float* t = (const float*)d_in[1];
  float* ws = (float*)d_ws;
  float* out = (float*)d_out;

  float* xn = ws;                       // 4096
  float* tn = ws + N_ROWS;              // 65536

  // FINE path ws layout (floats): xn | tn | bmv32[4096*2048] | xb | tb
  const size_t f_bmvF = (size_t)N_ROWS + M_TGT;
  const size_t f_xbF  = f_bmvF + (size_t)N_ROWS * NGRP;
  const size_t f_tbF  = f_xbF + ((size_t)N_ROWS * DDIM) / 2;
  const size_t need_fine = (f_tbF + ((size_t)M_TGT * DDIM) / 2) * sizeof(float);

  // MID path ws layout (floats): xn | tn | bmv[4096*512] | xb | tb
  const size_t f_bmvM = (size_t)N_ROWS + M_TGT;
  const size_t f_xbM  = f_bmvM + (size_t)N_ROWS * NCB;
  const size_t f_tbM  = f_xbM + ((size_t)N_ROWS * DDIM) / 2;
  const size_t need_mid = (f_tbM + ((size_t)M_TGT * DDIM) / 2) * sizeof(float);

  if (ws_size >= need_fine) {
    float* bmv32 = ws + f_bmvF;
    unsigned short* xb = (unsigned short*)(ws + f_xbF);
    unsigned short* tb = (unsigned short*)(ws + f_tbF);

    conv_norm_all<<<(N_ROWS + M_TGT) / 4, 256, 0, stream>>>(x, t, xb, tb, xn, tn);
    nn_gemm_bf16<<<(N_ROWS / GBM) * NCB, 256, 0, stream>>>(xb, tb, tn, bmv32);
    nn_exact_fine<<<N_ROWS, 256, 0, stream>>>(x, t, xn, tn, bmv32, out);
  } else if (ws_size >= need_mid) {
    float* bmv = ws + f_bmvM;
    unsigned short* xb = (unsigned short*)(ws + f_xbM);
    unsigned short* tb = (unsigned short*)(ws + f_tbM);

    conv_norm_all<<<(N_ROWS + M_TGT) / 4, 256, 0, stream>>>(x, t, xb, tb, xn, tn);
    nn_gemm_mid<<<(N_ROWS / GBM) * NCB, 256, 0, stream>>>(xb, tb, tn, bmv);
    nn_exact_mid<<<N_ROWS, 256, 0, stream>>>(x, t, xn, tn, bmv, out);
  } else {
    norms_kernel_fb<<<(N_ROWS + M_TGT) / 4, 256, 0, stream>>>(x, t, xn, tn);
    float* pmin = ws + N_ROWS + M_TGT;
    int*   pidx = (int*)(ws + N_ROWS + M_TGT + (size_t)N_ROWS * S_STRIPS);
    dim3 grid(N_ROWS / BM, S_STRIPS);
    nn_main_fb<<<grid, 256, 0, stream>>>(x, t, xn, tn, pmin, pidx);
    reduce_final_fb<<<(N_ROWS + 255) / 256, 256, 0, stream>>>(pmin, pidx, out);
  }
}

// Round 10
// 190.554 us; speedup vs baseline: 2.6774x; 1.0564x over previous
//
#include <hip/hip_runtime.h>
#include <float.h>
#include <math.h>

#define N_ROWS 4096
#define M_TGT  65536
#define DDIM   256

// ---------------------------------------------------------------------------
// Shared types/helpers
// ---------------------------------------------------------------------------
typedef short bf16x8 __attribute__((ext_vector_type(8)));
typedef float f32x4 __attribute__((ext_vector_type(4)));
typedef unsigned short ushort4_t __attribute__((ext_vector_type(4)));

__device__ inline unsigned short f2bf(float f) {
  union { float f; unsigned u; } c; c.f = f;
  unsigned u = c.u;
  unsigned r = (u + 0x7FFFu + ((u >> 16) & 1u)) >> 16;  // RNE
  return (unsigned short)r;
}

__device__ inline void gload_lds16(const void* g, void* l) {
  __builtin_amdgcn_global_load_lds(
      (const __attribute__((address_space(1))) void*)g,
      (__attribute__((address_space(3))) void*)l, 16, 0, 0);
}

#define MFMA16(a, b, c) __builtin_amdgcn_mfma_f32_16x16x32_bf16(a, b, c, 0, 0, 0)

// ---------------------------------------------------------------------------
// Fused fp32->bf16 convert + row norm for BOTH x and t. One wave per row.
// ---------------------------------------------------------------------------
__global__ __launch_bounds__(256) void conv_norm_all(
    const float* __restrict__ x, const float* __restrict__ t,
    unsigned short* __restrict__ xb, unsigned short* __restrict__ tb,
    float* __restrict__ xn, float* __restrict__ tn) {
  int wave = threadIdx.x >> 6;
  int lane = threadIdx.x & 63;
  int row  = blockIdx.x * 4 + wave;
  const float* src;
  unsigned short* db;
  float* dn;
  if (row < N_ROWS) {
    src = x + (size_t)row * DDIM;
    db  = xb + (size_t)row * DDIM;
    dn  = xn + row;
  } else {
    int r = row - N_ROWS;
    if (r >= M_TGT) return;
    src = t + (size_t)r * DDIM;
    db  = tb + (size_t)r * DDIM;
    dn  = tn + r;
  }
  float4 v = *(const float4*)(src + lane * 4);
  float ss = v.x * v.x + v.y * v.y + v.z * v.z + v.w * v.w;
  ushort4_t o;
  o[0] = f2bf(v.x); o[1] = f2bf(v.y); o[2] = f2bf(v.z); o[3] = f2bf(v.w);
  *(ushort4_t*)(db + lane * 4) = o;
  #pragma unroll
  for (int off = 32; off > 0; off >>= 1) ss += __shfl_xor(ss, off, 64);
  if (lane == 0) *dn = ss;
}

// ---------------------------------------------------------------------------
// bf16 MFMA screening GEMM — 128x256 tile, 8 waves (4 wt x 2 wx), BK=64.
// Same proven ingredients as r8/r9 (0-conflict XOR LDS layout, 2-barrier
// K-loop, operand-swapped 32-col-group epilogue) with halved per-FLOP
// overheads: 6 gload-issues/thread/K-step for 2x FLOP, half the barrier
// pairs per FLOP, LDS 52 KB -> 3 blocks/CU (24 waves).
// t is the MFMA A-operand: C-rows (lane-local cg*4+j) are TARGET cols;
// per-32-col group min = per-thread fmin chain + 2 shfl_xor.
// Output: bmv32[row][2048] group mins (identical layout to r9).
// ---------------------------------------------------------------------------
#define GBM 128                    // x rows per block
#define GBN2 256                   // t cols per block
#define GBK 64
#define NCB 512                    // 128-col tiles (mid path)
#define NGRP 2048                  // 32-col groups
#define MARGIN 1.5f

__global__ __launch_bounds__(512) void nn_gemm_bf16(
    const unsigned short* __restrict__ xb, const unsigned short* __restrict__ tb,
    const float* __restrict__ tn, float* __restrict__ bmv32) {
  __shared__ __align__(16) unsigned short sX[GBM * GBK];    // 16 KB (x rows)
  __shared__ __align__(16) unsigned short sT[GBN2 * GBK];   // 32 KB (t rows)
  __shared__ float smin[8][128];                            // 4 KB

  const int tid  = threadIdx.x;
  const int lane = tid & 63;
  const int wid  = tid >> 6;        // 0..7
  const int wt   = wid >> 1;        // t quarter (64 cols each)
  const int wx   = wid & 1;         // x half (64 rows each)
  const int ln   = lane & 15;
  const int cg   = lane >> 4;

  // XCD-aware, t-panel-reuse ordering (bijective: 8192 = 8 * 32 rb * 32 cbq)
  const int bid = blockIdx.x;
  const int xcd = bid & 7;
  const int w   = bid >> 3;
  const int rb  = w & 31;                    // fastest within XCD
  const int cb  = xcd * 32 + (w >> 5);       // 0..255 (256-col tiles)
  const int row0 = rb * GBM;
  const int col0 = cb * GBN2;

  // staging maps (proven): chunk q -> row=q>>3, phys slot=q&7,
  // logical slot s = (q&7) ^ (row&7); source k-offset = s*8
  int rqa[2], sqa[2];
  #pragma unroll
  for (int i = 0; i < 2; ++i) {
    int q = i * 512 + tid;
    rqa[i] = q >> 3;
    sqa[i] = (q & 7) ^ (rqa[i] & 7);
  }
  int rqb[4], sqb[4];
  #pragma unroll
  for (int i = 0; i < 4; ++i) {
    int q = i * 512 + tid;
    rqb[i] = q >> 3;
    sqb[i] = (q & 7) ^ (rqb[i] & 7);
  }
  char* sXc = (char*)sX;
  char* sTc = (char*)sT;

  f32x4 acc[4][4];
  const f32x4 zero = {0.0f, 0.0f, 0.0f, 0.0f};
  #pragma unroll
  for (int m = 0; m < 4; ++m)
    #pragma unroll
    for (int n = 0; n < 4; ++n) acc[m][n] = zero;

  #pragma unroll
  for (int kc = 0; kc < DDIM; kc += GBK) {
    __syncthreads();   // previous step's LDS reads complete
    #pragma unroll
    for (int i = 0; i < 2; ++i)
      gload_lds16(xb + (size_t)(row0 + rqa[i]) * DDIM + kc + sqa[i] * 8,
                  sXc + (i * 512 + tid) * 16);
    #pragma unroll
    for (int i = 0; i < 4; ++i)
      gload_lds16(tb + (size_t)(col0 + rqb[i]) * DDIM + kc + sqb[i] * 8,
                  sTc + (i * 512 + tid) * 16);
    __syncthreads();   // vmcnt(0) drained before barrier -> data ready

    bf16x8 tf[4][2], xf[4][2];
    #pragma unroll
    for (int m = 0; m < 4; ++m) {
      int r = wt * 64 + m * 16 + ln;
      #pragma unroll
      for (int kk = 0; kk < 2; ++kk) {
        int p = (kk * 4 + cg) ^ (r & 7);
        tf[m][kk] = *(const bf16x8*)(sTc + r * 128 + p * 16);
      }
    }
    #pragma unroll
    for (int n = 0; n < 4; ++n) {
      int r = wx * 64 + n * 16 + ln;
      #pragma unroll
      for (int kk = 0; kk < 2; ++kk) {
        int p = (kk * 4 + cg) ^ (r & 7);
        xf[n][kk] = *(const bf16x8*)(sXc + r * 128 + p * 16);
      }
    }
    #pragma unroll
    for (int kk = 0; kk < 2; ++kk)
      #pragma unroll
      for (int m = 0; m < 4; ++m)
        #pragma unroll
        for (int n = 0; n < 4; ++n)
          acc[m][n] = MFMA16(tf[m][kk], xf[n][kk], acc[m][n]);
  }

  // ---- epilogue: per-thread min per 32-col group (m-pair), per x-row ----
  float tnc[4][4];
  #pragma unroll
  for (int m = 0; m < 4; ++m)
    #pragma unroll
    for (int j = 0; j < 4; ++j)
      tnc[m][j] = tn[col0 + wt * 64 + m * 16 + cg * 4 + j];

  float vres[2][4];
  #pragma unroll
  for (int mh2 = 0; mh2 < 2; ++mh2) {
    #pragma unroll
    for (int n = 0; n < 4; ++n) {
      float v = FLT_MAX;
      #pragma unroll
      for (int mi = 0; mi < 2; ++mi) {
        int m = mh2 * 2 + mi;
        #pragma unroll
        for (int j = 0; j < 4; ++j)
          v = fminf(v, fmaf(-2.0f, acc[m][n][j], tnc[m][j]));
      }
      v = fminf(v, __shfl_xor(v, 16, 64));   // reduce over cg bit 0
      v = fminf(v, __shfl_xor(v, 32, 64));   // reduce over cg bit 1
      vres[mh2][n] = v;
    }
  }

  if (cg == 0) {
    #pragma unroll
    for (int mh2 = 0; mh2 < 2; ++mh2)
      #pragma unroll
      for (int n = 0; n < 4; ++n)
        smin[wt * 2 + mh2][wx * 64 + n * 16 + ln] = vres[mh2][n];
  }
  __syncthreads();
  if (tid < 128) {
    float4 o0, o1;
    o0.x = smin[0][tid]; o0.y = smin[1][tid];
    o0.z = smin[2][tid]; o0.w = smin[3][tid];
    o1.x = smin[4][tid]; o1.y = smin[5][tid];
    o1.z = smin[6][tid]; o1.w = smin[7][tid];
    float* dst = &bmv32[(size_t)(row0 + tid) * NGRP + (size_t)cb * 8];
    *(float4*)dst = o0;
    *(float4*)(dst + 4) = o1;
  }
}

// ---------------------------------------------------------------------------
// Fine candidate selection + exact fp32 verification. One block per row.
// Scan 2048 group-mins (8 KB contiguous), verify candidate 32-col groups
// (8 groups per pass, 32 threads each).
// ---------------------------------------------------------------------------
__global__ __launch_bounds__(256) void nn_exact_fine(
    const float* __restrict__ x, const float* __restrict__ t,
    const float* __restrict__ xn, const float* __restrict__ tn,
    const float* __restrict__ bmv32, float* __restrict__ out) {
  __shared__ float wmin[4];
  __shared__ int   clist[NGRP];
  __shared__ int   cnt;
  __shared__ float rv[256];
  __shared__ int   ri[256];

  const int row = blockIdx.x;
  const int tid = threadIdx.x;
  const float* brow = bmv32 + (size_t)row * NGRP;

  if (tid == 0) cnt = 0;
  float4 v0 = *(const float4*)(brow + tid * 8);
  float4 v1 = *(const float4*)(brow + tid * 8 + 4);
  float lmin = fminf(fminf(fminf(v0.x, v0.y), fminf(v0.z, v0.w)),
                     fminf(fminf(v1.x, v1.y), fminf(v1.z, v1.w)));
  #pragma unroll
  for (int off = 32; off > 0; off >>= 1)
    lmin = fminf(lmin, __shfl_xor(lmin, off, 64));
  if ((tid & 63) == 0) wmin[tid >> 6] = lmin;
  __syncthreads();
  const float thr =
      fminf(fminf(wmin[0], wmin[1]), fminf(wmin[2], wmin[3])) + MARGIN;

  {
    float vv[8] = {v0.x, v0.y, v0.z, v0.w, v1.x, v1.y, v1.z, v1.w};
    #pragma unroll
    for (int k = 0; k < 8; ++k) {
      if (vv[k] <= thr) {
        int p = atomicAdd(&cnt, 1);
        clist[p] = tid * 8 + k;
      }
    }
  }
  __syncthreads();
  const int nc = cnt;

  float best = FLT_MAX;
  int   bidx = 0x7FFFFFFF;
  const float xnr = xn[row];
  const float* xrow = x + (size_t)row * DDIM;

  for (int ci = 0; ci < nc; ci += 8) {
    int slot = ci + (tid >> 5);
    if (slot < nc) {
      int col = clist[slot] * 32 + (tid & 31);
      const float* trow = t + (size_t)col * DDIM;
      float acc = 0.0f;
      // serial k-ascending fp32 FMA chain (deterministic, exact per col)
      for (int kq = 0; kq < DDIM; kq += 4) {
        float4 xv = *(const float4*)(xrow + kq);
        float4 tv = *(const float4*)(trow + kq);
        acc = fmaf(xv.x, tv.x, acc);
        acc = fmaf(xv.y, tv.y, acc);
        acc = fmaf(xv.z, tv.z, acc);
        acc = fmaf(xv.w, tv.w, acc);
      }
      float d2 = xnr + tn[col] - 2.0f * acc;
      if (d2 < best || (d2 == best && col < bidx)) { best = d2; bidx = col; }
    }
  }
  rv[tid] = best; ri[tid] = bidx;
  __syncthreads();
  for (int s = 128; s >= 1; s >>= 1) {
    if (tid < s) {
      float vo = rv[tid + s]; int io = ri[tid + s];
      if (vo < rv[tid] || (vo == rv[tid] && io < ri[tid])) { rv[tid] = vo; ri[tid] = io; }
    }
    __syncthreads();
  }
  if (tid == 0) {
    out[row] = sqrtf(fmaxf(rv[0], 0.0f));
    out[N_ROWS + row] = (float)ri[0];
  }
}

// ---------------------------------------------------------------------------
// MIDDLE path (ws too small for bmv32): r8-proven coarse GEMM + exact.
// ---------------------------------------------------------------------------
#define MGBM 128
#define MGBN 128

__global__ __launch_bounds__(256) void nn_gemm_mid(
    const unsigned short* __restrict__ xb, const unsigned short* __restrict__ tb,
    const float* __restrict__ tn, float* __restrict__ bmv) {
  __shared__ __align__(16) unsigned short sX[MGBM * GBK];
  __shared__ __align__(16) unsigned short sT[MGBN * GBK];
  __shared__ float smin[2][128];

  const int tid  = threadIdx.x;
  const int lane = tid & 63;
  const int wid  = tid >> 6;
  const int wt   = wid >> 1;
  const int wx   = wid & 1;
  const int ln   = lane & 15;
  const int cg   = lane >> 4;

  const int bid = blockIdx.x;
  const int xcd = bid & 7;
  const int wgi = bid >> 3;
  const int rb  = wgi & 31;
  const int cb  = xcd * 64 + (wgi >> 5);
  const int row0 = rb * MGBM;
  const int col0 = cb * MGBN;

  int rq[4], sq[4];
  #pragma unroll
  for (int i = 0; i < 4; ++i) {
    int q = i * 256 + tid;
    rq[i] = q >> 3;
    sq[i] = (q & 7) ^ (rq[i] & 7);
  }
  char* sXc = (char*)sX;
  char* sTc = (char*)sT;

  f32x4 acc[4][4];
  const f32x4 zero = {0.0f, 0.0f, 0.0f, 0.0f};
  #pragma unroll
  for (int m = 0; m < 4; ++m)
    #pragma unroll
    for (int n = 0; n < 4; ++n) acc[m][n] = zero;

  #pragma unroll
  for (int kc = 0; kc < DDIM; kc += GBK) {
    __syncthreads();
    #pragma unroll
    for (int i = 0; i < 4; ++i)
      gload_lds16(xb + (size_t)(row0 + rq[i]) * DDIM + kc + sq[i] * 8,
                  sXc + i * 4096 + wid * 1024);
    #pragma unroll
    for (int i = 0; i < 4; ++i)
      gload_lds16(tb + (size_t)(col0 + rq[i]) * DDIM + kc + sq[i] * 8,
                  sTc + i * 4096 + wid * 1024);
    __syncthreads();

    bf16x8 tf[4][2], xf[4][2];
    #pragma unroll
    for (int m = 0; m < 4; ++m) {
      int r = wt * 64 + m * 16 + ln;
      #pragma unroll
      for (int kk = 0; kk < 2; ++kk) {
        int p = (kk * 4 + cg) ^ (r & 7);
        tf[m][kk] = *(const bf16x8*)(sTc + r * 128 + p * 16);
      }
    }
    #pragma unroll
    for (int n = 0; n < 4; ++n) {
      int r = wx * 64 + n * 16 + ln;
      #pragma unroll
      for (int kk = 0; kk < 2; ++kk) {
        int p = (kk * 4 + cg) ^ (r & 7);
        xf[n][kk] = *(const bf16x8*)(sXc + r * 128 + p * 16);
      }
    }
    #pragma unroll
    for (int kk = 0; kk < 2; ++kk)
      #pragma unroll
      for (int m = 0; m < 4; ++m)
        #pragma unroll
        for (int n = 0; n < 4; ++n)
          acc[m][n] = MFMA16(tf[m][kk], xf[n][kk], acc[m][n]);
  }

  float tnc[4][4];
  #pragma unroll
  for (int m = 0; m < 4; ++m)
    #pragma unroll
    for (int j = 0; j < 4; ++j)
      tnc[m][j] = tn[col0 + wt * 64 + m * 16 + cg * 4 + j];

  float res[4];
  #pragma unroll
  for (int n = 0; n < 4; ++n) {
    float v = FLT_MAX;
    #pragma unroll
    for (int m = 0; m < 4; ++m)
      #pragma unroll
      for (int j = 0; j < 4; ++j)
        v = fminf(v, fmaf(-2.0f, acc[m][n][j], tnc[m][j]));
    v = fminf(v, __shfl_xor(v, 16, 64));
    v = fminf(v, __shfl_xor(v, 32, 64));
    res[n] = v;
  }

  __syncthreads();
  if (cg == 0) {
    #pragma unroll
    for (int n = 0; n < 4; ++n)
      smin[wt][wx * 64 + n * 16 + ln] = res[n];
  }
  __syncthreads();
  if (tid < 128)
    bmv[(size_t)(row0 + tid) * NCB + cb] = fminf(smin[0][tid], smin[1][tid]);
}

__global__ __launch_bounds__(256) void nn_exact_mid(
    const float* __restrict__ x, const float* __restrict__ t,
    const float* __restrict__ xn, const float* __restrict__ tn,
    const float* __restrict__ bmv, float* __restrict__ out) {
  __shared__ float sv[NCB];
  __shared__ int   clist[NCB];
  __shared__ int   cnt;
  __shared__ float wmin[4];
  __shared__ float rv[256];
  __shared__ int   ri[256];

  const int row = blockIdx.x;
  const int tid = threadIdx.x;

  if (tid == 0) cnt = 0;
  float lmin = FLT_MAX;
  #pragma unroll
  for (int e = tid; e < NCB; e += 256) {
    float v = bmv[(size_t)row * NCB + e];
    sv[e] = v;
    lmin = fminf(lmin, v);
  }
  #pragma unroll
  for (int off = 32; off > 0; off >>= 1) lmin = fminf(lmin, __shfl_xor(lmin, off, 64));
  if ((tid & 63) == 0) wmin[tid >> 6] = lmin;
  __syncthreads();
  const float g = fminf(fminf(wmin[0], wmin[1]), fminf(wmin[2], wmin[3]));

  #pragma unroll
  for (int e = tid; e < NCB; e += 256) {
    if (sv[e] <= g + MARGIN) {
      int p = atomicAdd(&cnt, 1);
      clist[p] = e;
    }
  }
  __syncthreads();
  const int nc = cnt;

  float best = FLT_MAX;
  int   bidx = 0x7FFFFFFF;
  const float xnr = xn[row];
  const float* xrow = x + (size_t)row * DDIM;

  for (int ci = 0; ci < nc; ci += 2) {
    int slot = ci + (tid >> 7);
    if (slot < nc) {
      int col = clist[slot] * 128 + (tid & 127);
      const float* trow = t + (size_t)col * DDIM;
      float acc = 0.0f;
      for (int kq = 0; kq < DDIM; kq += 4) {
        float4 xv = *(const float4*)(xrow + kq);
        float4 tv = *(const float4*)(trow + kq);
        acc = fmaf(xv.x, tv.x, acc);
        acc = fmaf(xv.y, tv.y, acc);
        acc = fmaf(xv.z, tv.z, acc);
        acc = fmaf(xv.w, tv.w, acc);
      }
      float d2 = xnr + tn[col] - 2.0f * acc;
      if (d2 < best || (d2 == best && col < bidx)) { best = d2; bidx = col; }
    }
  }
  rv[tid] = best; ri[tid] = bidx;
  __syncthreads();
  for (int s = 128; s >= 1; s >>= 1) {
    if (tid < s) {
      float vo = rv[tid + s]; int io = ri[tid + s];
      if (vo < rv[tid] || (vo == rv[tid] && io < ri[tid])) { rv[tid] = vo; ri[tid] = io; }
    }
    __syncthreads();
  }
  if (tid == 0) {
    out[row] = sqrtf(fmaxf(rv[0], 0.0f));
    out[N_ROWS + row] = (float)ri[0];
  }
}

// ---------------------------------------------------------------------------
// Fallback fp32 path (if ws tiny) — round-1 proven
// ---------------------------------------------------------------------------
#define BM 64
#define BN 64
#define KC 16
#define S_STRIPS 32
#define PADM 68

__global__ __launch_bounds__(256) void norms_kernel_fb(
    const float* __restrict__ x, const float* __restrict__ t,
    float* __restrict__ xn, float* __restrict__ tn) {
  int wave = threadIdx.x >> 6;
  int lane = threadIdx.x & 63;
  int row  = blockIdx.x * 4 + wave;
  const float* src; float* dst;
  if (row < N_ROWS) { src = x + (size_t)row * DDIM; dst = xn + row; }
  else {
    int r = row - N_ROWS;
    if (r >= M_TGT) return;
    src = t + (size_t)r * DDIM; dst = tn + r;
  }
  float4 v = *(const float4*)(src + lane * 4);
  float s = v.x * v.x + v.y * v.y + v.z * v.z + v.w * v.w;
  #pragma unroll
  for (int off = 32; off > 0; off >>= 1) s += __shfl_xor(s, off, 64);
  if (lane == 0) *dst = s;
}

__global__ __launch_bounds__(256) void nn_main_fb(
    const float* __restrict__ x, const float* __restrict__ t,
    const float* __restrict__ xn, const float* __restrict__ tn,
    float* __restrict__ pmin, int* __restrict__ pidx) {
  __shared__ float sx[KC][PADM];
  __shared__ float st[KC][PADM];
  const int tid = threadIdx.x;
  const int rb = blockIdx.x;
  const int strip = blockIdx.y;
  const int tx = tid & 15, ty = tid >> 4;
  const int row0 = rb * BM;
  const int col_start = strip * (M_TGT / S_STRIPS);
  const int ntiles = (M_TGT / S_STRIPS) / BN;
  const int srow = tid >> 2;
  const int kq = (tid & 3) * 4;

  float runMin[4]; int runIdx[4];
  #pragma unroll
  for (int r = 0; r < 4; ++r) { runMin[r] = FLT_MAX; runIdx[r] = 0; }
  float xnr[4];
  #pragma unroll
  for (int r = 0; r < 4; ++r) xnr[r] = xn[row0 + ty * 4 + r];

  for (int tile = 0; tile < ntiles; ++tile) {
    const int cbk = col_start + tile * BN;
    float acc[4][4];
    #pragma unroll
    for (int r = 0; r < 4; ++r)
      #pragma unroll
      for (int c = 0; c < 4; ++c) acc[r][c] = 0.0f;
    #pragma unroll 1
    for (int kc = 0; kc < DDIM; kc += KC) {
      float4 xv = *(const float4*)(x + (size_t)(row0 + srow) * DDIM + kc + kq);
      float4 tv = *(const float4*)(t + (size_t)(cbk + srow) * DDIM + kc + kq);
      __syncthreads();
      sx[kq + 0][srow] = xv.x; sx[kq + 1][srow] = xv.y;
      sx[kq + 2][srow] = xv.z; sx[kq + 3][srow] = xv.w;
      st[kq + 0][srow] = tv.x; st[kq + 1][srow] = tv.y;
      st[kq + 2][srow] = tv.z; st[kq + 3][srow] = tv.w;
      __syncthreads();
      #pragma unroll
      for (int k = 0; k < KC; ++k) {
        float4 xa = *(const float4*)&sx[k][ty * 4];
        float4 tb2 = *(const float4*)&st[k][tx * 4];
        float xr[4] = {xa.x, xa.y, xa.z, xa.w};
        float tc[4] = {tb2.x, tb2.y, tb2.z, tb2.w};
        #pragma unroll
        for (int r = 0; r < 4; ++r)
          #pragma unroll
          for (int c = 0; c < 4; ++c)
            acc[r][c] = fmaf(xr[r], tc[c], acc[r][c]);
      }
    }
    #pragma unroll
    for (int r = 0; r < 4; ++r)
      #pragma unroll
      for (int c = 0; c < 4; ++c) {
        int col = cbk + tx * 4 + c;
        float d2 = xnr[r] + tn[col] - 2.0f * acc[r][c];
        if (d2 < runMin[r]) { runMin[r] = d2; runIdx[r] = col; }
      }
  }
  __syncthreads();
  float* redv = &sx[0][0];
  int*   redi = (int*)&st[0][0];
  #pragma unroll
  for (int r = 0; r < 4; ++r) {
    int lrow = ty * 4 + r;
    redv[lrow * 16 + tx] = runMin[r];
    redi[lrow * 16 + tx] = runIdx[r];
  }
  __syncthreads();
  if (tid < 64) {
    float best = FLT_MAX; int bi = 0;
    #pragma unroll
    for (int j = 0; j < 16; ++j) {
      float v = redv[tid * 16 + j];
      int   i = redi[tid * 16 + j];
      if (v < best || (v == best && i < bi)) { best = v; bi = i; }
    }
    int grow = row0 + tid;
    pmin[(size_t)grow * S_STRIPS + strip] = best;
    pidx[(size_t)grow * S_STRIPS + strip] = bi;
  }
}

__global__ __launch_bounds__(256) void reduce_final_fb(
    const float* __restrict__ pmin, const int* __restrict__ pidx,
    float* __restrict__ out) {
  int row = blockIdx.x * 256 + threadIdx.x;
  if (row >= N_ROWS) return;
  float best = FLT_MAX; int bi = 0;
  #pragma unroll 4
  for (int s = 0; s < S_STRIPS; ++s) {
    float v = pmin[(size_t)row * S_STRIPS + s];
    int   i = pidx[(size_t)row * S_STRIPS + s];
    if (v < best || (v == best && i < bi)) { best = v; bi = i; }
  }
  out[row] = sqrtf(fmaxf(best, 0.0f));
  out[N_ROWS + row] = (float)bi;
}

// ---------------------------------------------------------------------------
extern "C" void kernel_launch(void* const* d_in, const int* in_sizes, int n_in,
                              void* d_out, int out_size, void* d_ws, size_t ws_size,
                              hipStream_t stream) {
  const float* x = (const float*)d_in[0];
  const float* t = (const float*)d_in[1];
  float* ws = (float*)d_ws;
  float* out = (float*)d_out;

  float* xn = ws;                       // 4096
  float* tn = ws + N_ROWS;              // 65536

  // FINE path ws layout (floats): xn | tn | bmv32[4096*2048] | xb | tb
  const size_t f_bmvF = (size_t)N_ROWS + M_TGT;
  const size_t f_xbF  = f_bmvF + (size_t)N_ROWS * NGRP;
  const size_t f_tbF  = f_xbF + ((size_t)N_ROWS * DDIM) / 2;
  const size_t need_fine = (f_tbF + ((size_t)M_TGT * DDIM) / 2) * sizeof(float);

  // MID path ws layout (floats): xn | tn | bmv[4096*512] | xb | tb
  const size_t f_bmvM = (size_t)N_ROWS + M_TGT;
  const size_t f_xbM  = f_bmvM + (size_t)N_ROWS * NCB;
  const size_t f_tbM  = f_xbM + ((size_t)N_ROWS * DDIM) / 2;
  const size_t need_mid = (f_tbM + ((size_t)M_TGT * DDIM) / 2) * sizeof(float);

  if (ws_size >= need_fine) {
    float* bmv32 = ws + f_bmvF;
    unsigned short* xb = (unsigned short*)(ws + f_xbF);
    unsigned short* tb = (unsigned short*)(ws + f_tbF);

    conv_norm_all<<<(N_ROWS + M_TGT) / 4, 256, 0, stream>>>(x, t, xb, tb, xn, tn);
    nn_gemm_bf16<<<(N_ROWS / GBM) * (M_TGT / GBN2), 512, 0, stream>>>(xb, tb, tn, bmv32);
    nn_exact_fine<<<N_ROWS, 256, 0, stream>>>(x, t, xn, tn, bmv32, out);
  } else if (ws_size >= need_mid) {
    float* bmv = ws + f_bmvM;
    unsigned short* xb = (unsigned short*)(ws + f_xbM);
    unsigned short* tb = (unsigned short*)(ws + f_tbM);

    conv_norm_all<<<(N_ROWS + M_TGT) / 4, 256, 0, stream>>>(x, t, xb, tb, xn, tn);
    nn_gemm_mid<<<(N_ROWS / MGBM) * NCB, 256, 0, stream>>>(xb, tb, tn, bmv);
    nn_exact_mid<<<N_ROWS, 256, 0, stream>>>(x, t, xn, tn, bmv, out);
  } else {
    norms_kernel_fb<<<(N_ROWS + M_TGT) / 4, 256, 0, stream>>>(x, t, xn, tn);
    float* pmin = ws + N_ROWS + M_TGT;
    int*   pidx = (int*)(ws + N_ROWS + M_TGT + (size_t)N_ROWS * S_STRIPS);
    dim3 grid(N_ROWS / BM, S_STRIPS);
    nn_main_fb<<<grid, 256, 0, stream>>>(x, t, xn, tn, pmin, pidx);
    reduce_final_fb<<<(N_ROWS + 255) / 256, 256, 0, stream>>>(pmin, pidx, out);
  }
}